// Round 5
// baseline (693.425 us; speedup 1.0000x reference)
//
#include <hip/hip_runtime.h>
#include <hip/hip_bf16.h>

#define NN 50000
#define EE 800000
#define ETOT 850000
#define NG 500
#define NBLK ((NN + 255) / 256)  // 196 scan blocks

// int64 vs int32 index detect: node ids < 50000, so int64 => odd words all 0.
__global__ void k_detect(const int* __restrict__ ei, int* __restrict__ flag) {
    unsigned long long b = __ballot(ei[2 * threadIdx.x + 1] != 0);
    if (threadIdx.x == 0) *flag = b ? 1 : 2;
}

// edge list (either width) -> int32 src/dst with self-loops appended.
__global__ __launch_bounds__(256) void k_prep(const int* __restrict__ ei,
                                              const int* __restrict__ flag,
                                              int* __restrict__ src32,
                                              int* __restrict__ dst32) {
    int e = blockIdx.x * 256 + threadIdx.x;
    if (e >= ETOT) return;
    int st = *flag;
    if (e < EE) {
        src32[e] = ei[(size_t)st * e];
        dst32[e] = ei[(size_t)st * (EE + e)];
    } else {
        src32[e] = dst32[e] = e - EE;  // self-loop
    }
}

__global__ __launch_bounds__(256) void k_zero_deg(int* __restrict__ deg) {
    int i = blockIdx.x * 256 + threadIdx.x;
    if (i < NN) deg[i] = 0;
}

__global__ __launch_bounds__(256) void k_hist(const int* __restrict__ dst32,
                                              int* __restrict__ deg) {
    int e = blockIdx.x * 256 + threadIdx.x;
    if (e < ETOT) atomicAdd(&deg[dst32[e]], 1);
}

// ---- 3-phase multi-block exclusive scan of deg[NN] ----
__global__ __launch_bounds__(256) void k_blocksum(const int* __restrict__ deg,
                                                  int* __restrict__ bsum) {
    __shared__ int l[256];
    int gid = blockIdx.x * 256 + threadIdx.x;
    int tid = threadIdx.x;
    l[tid] = (gid < NN) ? deg[gid] : 0;
    __syncthreads();
    for (int o = 128; o > 0; o >>= 1) {
        if (tid < o) l[tid] += l[tid + o];
        __syncthreads();
    }
    if (tid == 0) bsum[blockIdx.x] = l[0];
}

__global__ __launch_bounds__(256) void k_scan_bsum(const int* __restrict__ bsum,
                                                   int* __restrict__ boff) {
    __shared__ int l[256];
    int tid = threadIdx.x;
    int v = (tid < NBLK) ? bsum[tid] : 0;
    l[tid] = v;
    __syncthreads();
    for (int d = 1; d < 256; d <<= 1) {
        int t = (tid >= d) ? l[tid - d] : 0;
        __syncthreads();
        l[tid] += t;
        __syncthreads();
    }
    if (tid < NBLK) boff[tid] = l[tid] - v;  // exclusive
}

__global__ __launch_bounds__(256) void k_scan_final(const int* __restrict__ deg,
                                                    const int* __restrict__ boff,
                                                    int* __restrict__ rowptr,
                                                    int* __restrict__ cursor) {
    __shared__ int l[256];
    int gid = blockIdx.x * 256 + threadIdx.x;
    int tid = threadIdx.x;
    int v = (gid < NN) ? deg[gid] : 0;
    l[tid] = v;
    __syncthreads();
    for (int d = 1; d < 256; d <<= 1) {
        int t = (tid >= d) ? l[tid - d] : 0;
        __syncthreads();
        l[tid] += t;
        __syncthreads();
    }
    int ex = l[tid] - v + boff[blockIdx.x];
    if (gid < NN) { rowptr[gid] = ex; cursor[gid] = ex; }
    if (gid == 0) rowptr[NN] = ETOT;  // total incl. self-loops is a constant
}

__global__ __launch_bounds__(256) void k_scatter(const int* __restrict__ src32,
                                                 const int* __restrict__ dst32,
                                                 int* __restrict__ cursor,
                                                 int* __restrict__ csr_src) {
    int e = blockIdx.x * 256 + threadIdx.x;
    if (e >= ETOT) return;
    int pos = atomicAdd(&cursor[dst32[e]], 1);
    csr_src[pos] = src32[e];
}

// C[M,256] = A[M,K] @ B[K,256], fp32 tiled. BM=128,BN=64(one head),BK=16,
// 256 thr, 8x4/thr (halves LDS traffic per FMA vs 4x4).
// C stored INTERLEAVED: C[m*256 + dim*4 + head]. Fused alpha_s/alpha_d epilogue.
template <int K>
__global__ __launch_bounds__(256) void k_gemm(const float* __restrict__ A,
                                              const float* __restrict__ B,
                                              const float* __restrict__ asrc,
                                              const float* __restrict__ adst,
                                              float* __restrict__ C,
                                              float* __restrict__ os,
                                              float* __restrict__ od, int M) {
    __shared__ float As[16][132];  // [k][m], pad 4 keeps b128 frags 16B-aligned
    __shared__ float Bs[16][68];   // [k][n]
    const int m0 = blockIdx.x * 128, head = blockIdx.y, n0 = head * 64;
    const int tid = threadIdx.x;
    const int tx = tid & 15, ty = tid >> 4;  // tx: 4-col group, ty: 8-row group
    float acc[8][4] = {};
    for (int k0 = 0; k0 < K; k0 += 16) {
        {   // A tile: 128 rows x 16 k
            int c = tid & 15, r0 = tid >> 4;
#pragma unroll
            for (int rr = 0; rr < 8; ++rr) {
                int r = r0 + rr * 16, gm = m0 + r;
                As[c][r] = (gm < M) ? A[gm * K + k0 + c] : 0.f;
            }
        }
        {   // B tile: 16 k x 64 n
            int j = tid & 63, kb = tid >> 6;
#pragma unroll
            for (int cc = 0; cc < 4; ++cc) {
                int k = kb + cc * 4;
                Bs[k][j] = B[(k0 + k) * 256 + n0 + j];
            }
        }
        __syncthreads();
#pragma unroll
        for (int k = 0; k < 16; ++k) {
            float a[8], b[4];
            *(float4*)&a[0] = *(const float4*)&As[k][ty * 8];
            *(float4*)&a[4] = *(const float4*)&As[k][ty * 8 + 4];
            *(float4*)&b[0] = *(const float4*)&Bs[k][tx * 4];
#pragma unroll
            for (int i = 0; i < 8; ++i)
#pragma unroll
                for (int j = 0; j < 4; ++j) acc[i][j] += a[i] * b[j];
        }
        __syncthreads();
    }
#pragma unroll
    for (int i = 0; i < 8; ++i) {
        int gm = m0 + ty * 8 + i;
        if (gm < M) {
#pragma unroll
            for (int j = 0; j < 4; ++j)
                C[gm * 256 + (tx * 4 + j) * 4 + head] = acc[i][j];
        }
    }
    // fused alpha_s / alpha_d (reduce over tx: 16-lane groups share ty)
    float4 av = *(const float4*)&asrc[head * 64 + tx * 4];
    float4 dv = *(const float4*)&adst[head * 64 + tx * 4];
    float ps[8], pd[8];
#pragma unroll
    for (int i = 0; i < 8; ++i) {
        ps[i] = acc[i][0] * av.x + acc[i][1] * av.y + acc[i][2] * av.z + acc[i][3] * av.w;
        pd[i] = acc[i][0] * dv.x + acc[i][1] * dv.y + acc[i][2] * dv.z + acc[i][3] * dv.w;
    }
#pragma unroll
    for (int off = 1; off < 16; off <<= 1) {
#pragma unroll
        for (int i = 0; i < 8; ++i) {
            ps[i] += __shfl_xor(ps[i], off);
            pd[i] += __shfl_xor(pd[i], off);
        }
    }
    if (tx == 0) {
#pragma unroll
        for (int i = 0; i < 8; ++i) {
            int gm = m0 + ty * 8 + i;
            if (gm < M) {
                os[gm * 4 + head] = ps[i];
                od[gm * 4 + head] = pd[i];
            }
        }
    }
}

__device__ __forceinline__ float lrelu_exp(float x) {
    x = x > 0.f ? x : 0.2f * x;
    return __expf(x);
}

// Broadcast-MAC over one chunk of <=64 edges held in (s, al) lane registers.
// 4-wide manual unroll: 4 independent global_load_dwordx4 in flight per wave
// (dynamic-trip loop alone keeps only ~1 outstanding -> latency-bound).
__device__ __forceinline__ float bcast_mac(int s, float4 al, int cnt, int lane,
                                           const float* __restrict__ h) {
    float acc = 0.f;
    int j = 0;
    for (; j + 4 <= cnt; j += 4) {
        int s_0 = __shfl(s, j), s_1 = __shfl(s, j + 1);
        int s_2 = __shfl(s, j + 2), s_3 = __shfl(s, j + 3);
        float4 h0 = *(const float4*)(h + s_0 * 256 + lane * 4);
        float4 h1 = *(const float4*)(h + s_1 * 256 + lane * 4);
        float4 h2 = *(const float4*)(h + s_2 * 256 + lane * 4);
        float4 h3 = *(const float4*)(h + s_3 * 256 + lane * 4);
        float a00 = __shfl(al.x, j), a01 = __shfl(al.y, j), a02 = __shfl(al.z, j), a03 = __shfl(al.w, j);
        float a10 = __shfl(al.x, j + 1), a11 = __shfl(al.y, j + 1), a12 = __shfl(al.z, j + 1), a13 = __shfl(al.w, j + 1);
        float a20 = __shfl(al.x, j + 2), a21 = __shfl(al.y, j + 2), a22 = __shfl(al.z, j + 2), a23 = __shfl(al.w, j + 2);
        float a30 = __shfl(al.x, j + 3), a31 = __shfl(al.y, j + 3), a32 = __shfl(al.z, j + 3), a33 = __shfl(al.w, j + 3);
        acc += a00 * h0.x + a01 * h0.y + a02 * h0.z + a03 * h0.w;
        acc += a10 * h1.x + a11 * h1.y + a12 * h1.z + a13 * h1.w;
        acc += a20 * h2.x + a21 * h2.y + a22 * h2.z + a23 * h2.w;
        acc += a30 * h3.x + a31 * h3.y + a32 * h3.z + a33 * h3.w;
    }
    for (; j < cnt; ++j) {
        int sj = __shfl(s, j);
        float a0 = __shfl(al.x, j), a1 = __shfl(al.y, j);
        float a2 = __shfl(al.z, j), a3 = __shfl(al.w, j);
        float4 hv = *(const float4*)(h + sj * 256 + lane * 4);
        acc += a0 * hv.x + a1 * hv.y + a2 * hv.z + a3 * hv.w;
    }
    return acc;
}

// Wave per dst node; avg degree = 17 so chunk 0 is almost always the only one.
// Pass 1 computes den AND caches chunk-0 (s, exp) in registers; pass 2 reuses.
__global__ __launch_bounds__(256) void k_aggr(const int* __restrict__ rowptr,
                                              const int* __restrict__ csr_src,
                                              const float* __restrict__ as_,
                                              const float* __restrict__ ad_,
                                              const float* __restrict__ h,
                                              const float* __restrict__ bias,
                                              float* __restrict__ out) {
    int d = (blockIdx.x * 256 + threadIdx.x) >> 6;
    int lane = threadIdx.x & 63;
    if (d >= NN) return;
    int beg = rowptr[d], end = rowptr[d + 1];
    float4 adv = *(const float4*)(ad_ + d * 4);

    // pass 1: denominator + chunk-0 register cache
    int s0 = 0;
    float4 u0 = make_float4(0.f, 0.f, 0.f, 0.f);
    float4 den = make_float4(0.f, 0.f, 0.f, 0.f);
    int i0 = beg + lane;
    if (i0 < end) {
        s0 = csr_src[i0];
        float4 sv = *(const float4*)(as_ + s0 * 4);
        u0.x = lrelu_exp(sv.x + adv.x);
        u0.y = lrelu_exp(sv.y + adv.y);
        u0.z = lrelu_exp(sv.z + adv.z);
        u0.w = lrelu_exp(sv.w + adv.w);
        den = u0;
    }
    for (int i = i0 + 64; i < end; i += 64) {
        int s = csr_src[i];
        float4 sv = *(const float4*)(as_ + s * 4);
        den.x += lrelu_exp(sv.x + adv.x);
        den.y += lrelu_exp(sv.y + adv.y);
        den.z += lrelu_exp(sv.z + adv.z);
        den.w += lrelu_exp(sv.w + adv.w);
    }
#pragma unroll
    for (int off = 32; off > 0; off >>= 1) {
        den.x += __shfl_xor(den.x, off);
        den.y += __shfl_xor(den.y, off);
        den.z += __shfl_xor(den.z, off);
        den.w += __shfl_xor(den.w, off);
    }
    float4 dinv = make_float4(0.25f / den.x, 0.25f / den.y,
                              0.25f / den.z, 0.25f / den.w);

    // pass 2: chunk 0 from registers
    float4 al0 = make_float4(u0.x * dinv.x, u0.y * dinv.y,
                             u0.z * dinv.z, u0.w * dinv.w);
    int cnt0 = end - beg;
    if (cnt0 > 64) cnt0 = 64;
    float acc = bcast_mac(s0, al0, cnt0, lane, h);

    // rare chunks >= 1: recompute
    for (int chunk = beg + 64; chunk < end; chunk += 64) {
        int i = chunk + lane;
        int s = 0;
        float4 al = make_float4(0.f, 0.f, 0.f, 0.f);
        if (i < end) {
            s = csr_src[i];
            float4 sv = *(const float4*)(as_ + s * 4);
            al.x = lrelu_exp(sv.x + adv.x) * dinv.x;
            al.y = lrelu_exp(sv.y + adv.y) * dinv.y;
            al.z = lrelu_exp(sv.z + adv.z) * dinv.z;
            al.w = lrelu_exp(sv.w + adv.w) * dinv.w;
        }
        int cnt = end - chunk;
        if (cnt > 64) cnt = 64;
        acc += bcast_mac(s, al, cnt, lane, h);
    }
    float v = acc + bias[lane];
    out[d * 64 + lane] = v > 0.f ? v : 0.f;
}

// batch is SORTED: binary-search the node range per graph -> no atomics.
__global__ __launch_bounds__(64) void k_pool_fc(const float* __restrict__ x3,
                                                const int* __restrict__ batch,
                                                const int* __restrict__ flag,
                                                const float* __restrict__ fcW,
                                                const float* __restrict__ fcb,
                                                float* __restrict__ out) {
    int g = blockIdx.x;
    int d = threadIdx.x;  // 64
    int st = *flag;
    int lo = 0, hi = NN;
    while (lo < hi) { int mid = (lo + hi) >> 1; if (batch[(size_t)st * mid] < g) lo = mid + 1; else hi = mid; }
    int start = lo;
    hi = NN;
    while (lo < hi) { int mid = (lo + hi) >> 1; if (batch[(size_t)st * mid] < g + 1) lo = mid + 1; else hi = mid; }
    int end = lo;
    float sum = 0.f;
    for (int n = start; n < end; ++n) sum += x3[n * 64 + d];
    float c = (float)(end - start);
    if (c < 1.f) c = 1.f;
    float p = sum / c;
#pragma unroll
    for (int o = 0; o < 16; ++o) {
        float v = p * fcW[d * 16 + o];
#pragma unroll
        for (int off = 32; off > 0; off >>= 1) v += __shfl_down(v, off);
        if (d == 0) out[g * 16 + o] = v + fcb[o];
    }
}

extern "C" void kernel_launch(void* const* d_in, const int* in_sizes, int n_in,
                              void* d_out, int out_size, void* d_ws, size_t ws_size,
                              hipStream_t stream) {
    const float* x   = (const float*)d_in[0];
    const int*   ei  = (const int*)d_in[1];
    const int*   bat = (const int*)d_in[2];
    const float* W1  = (const float*)d_in[3];
    const float* a1s = (const float*)d_in[4];
    const float* a1d = (const float*)d_in[5];
    const float* b1  = (const float*)d_in[6];
    const float* W2  = (const float*)d_in[7];
    const float* a2s = (const float*)d_in[8];
    const float* a2d = (const float*)d_in[9];
    const float* b2  = (const float*)d_in[10];
    const float* fcW = (const float*)d_in[11];
    const float* fcb = (const float*)d_in[12];
    float* out = (float*)d_out;

    float* ws = (float*)d_ws;
    int* flag = (int*)d_ws;                       // [1] (+pad to 256)
    float* h     = ws + 256;                      // [N,256] interleaved [n][dim][head]
    float* as_   = h + (size_t)NN * 256;          // [N,4]
    float* ad_   = as_ + NN * 4;                  // [N,4]
    float* xacc  = ad_ + NN * 4;                  // [N,64]
    int* src32   = (int*)(xacc + (size_t)NN * 64);// [E]
    int* dst32   = src32 + ETOT;                  // [E]
    int* deg     = dst32 + ETOT;                  // [N]
    int* rowptr  = deg + NN;                      // [N+1]
    int* cursor  = rowptr + NN + 1;               // [N]
    int* csr_src = cursor + NN;                   // [E]
    int* bsum    = csr_src + ETOT;                // [NBLK]
    int* boff    = bsum + NBLK;                   // [NBLK]

    const int eb = (ETOT + 255) / 256;    // 3321
    const int wb = (NN * 64 + 255) / 256; // 12500 (wave-per-node blocks)

    // ---- one-time per call: indices + dst-CSR ----
    k_detect<<<1, 64, 0, stream>>>(ei, flag);
    k_prep<<<eb, 256, 0, stream>>>(ei, flag, src32, dst32);
    k_zero_deg<<<(NN + 255) / 256, 256, 0, stream>>>(deg);
    k_hist<<<eb, 256, 0, stream>>>(dst32, deg);
    k_blocksum<<<NBLK, 256, 0, stream>>>(deg, bsum);
    k_scan_bsum<<<1, 256, 0, stream>>>(bsum, boff);
    k_scan_final<<<NBLK, 256, 0, stream>>>(deg, boff, rowptr, cursor);
    k_scatter<<<eb, 256, 0, stream>>>(src32, dst32, cursor, csr_src);

    const dim3 g1((NN + 127) / 128, 4);
    // ---- layer 1 ----
    k_gemm<128><<<g1, 256, 0, stream>>>(x, W1, a1s, a1d, h, as_, ad_, NN);
    k_aggr<<<wb, 256, 0, stream>>>(rowptr, csr_src, as_, ad_, h, b1, xacc);
    // ---- layer 2 ----
    k_gemm<64><<<g1, 256, 0, stream>>>(xacc, W2, a2s, a2d, h, as_, ad_, NN);
    k_aggr<<<wb, 256, 0, stream>>>(rowptr, csr_src, as_, ad_, h, b2, xacc);
    // ---- pool + fc ----
    k_pool_fc<<<NG, 64, 0, stream>>>(xacc, bat, flag, fcW, fcb, out);
}

// Round 6
// 525.338 us; speedup vs baseline: 1.3200x; 1.3200x over previous
//
#include <hip/hip_runtime.h>
#include <hip/hip_bf16.h>
#include <hip/hip_fp16.h>

#define NN 50000
#define EE 800000
#define ETOT 850000
#define NG 500
#define NBLK ((NN + 255) / 256)  // 196 scan blocks

// int64 vs int32 index detect: node ids < 50000, so int64 => odd words all 0.
__global__ void k_detect(const int* __restrict__ ei, int* __restrict__ flag) {
    unsigned long long b = __ballot(ei[2 * threadIdx.x + 1] != 0);
    if (threadIdx.x == 0) *flag = b ? 1 : 2;
}

// edge list (either width) -> int32 src/dst with self-loops appended.
__global__ __launch_bounds__(256) void k_prep(const int* __restrict__ ei,
                                              const int* __restrict__ flag,
                                              int* __restrict__ src32,
                                              int* __restrict__ dst32) {
    int e = blockIdx.x * 256 + threadIdx.x;
    if (e >= ETOT) return;
    int st = *flag;
    if (e < EE) {
        src32[e] = ei[(size_t)st * e];
        dst32[e] = ei[(size_t)st * (EE + e)];
    } else {
        src32[e] = dst32[e] = e - EE;  // self-loop
    }
}

__global__ __launch_bounds__(256) void k_zero_deg(int* __restrict__ deg) {
    int i = blockIdx.x * 256 + threadIdx.x;
    if (i < NN) deg[i] = 0;
}

__global__ __launch_bounds__(256) void k_hist(const int* __restrict__ dst32,
                                              int* __restrict__ deg) {
    int e = blockIdx.x * 256 + threadIdx.x;
    if (e < ETOT) atomicAdd(&deg[dst32[e]], 1);
}

// ---- 3-phase multi-block exclusive scan of deg[NN] ----
__global__ __launch_bounds__(256) void k_blocksum(const int* __restrict__ deg,
                                                  int* __restrict__ bsum) {
    __shared__ int l[256];
    int gid = blockIdx.x * 256 + threadIdx.x;
    int tid = threadIdx.x;
    l[tid] = (gid < NN) ? deg[gid] : 0;
    __syncthreads();
    for (int o = 128; o > 0; o >>= 1) {
        if (tid < o) l[tid] += l[tid + o];
        __syncthreads();
    }
    if (tid == 0) bsum[blockIdx.x] = l[0];
}

__global__ __launch_bounds__(256) void k_scan_bsum(const int* __restrict__ bsum,
                                                   int* __restrict__ boff) {
    __shared__ int l[256];
    int tid = threadIdx.x;
    int v = (tid < NBLK) ? bsum[tid] : 0;
    l[tid] = v;
    __syncthreads();
    for (int d = 1; d < 256; d <<= 1) {
        int t = (tid >= d) ? l[tid - d] : 0;
        __syncthreads();
        l[tid] += t;
        __syncthreads();
    }
    if (tid < NBLK) boff[tid] = l[tid] - v;  // exclusive
}

__global__ __launch_bounds__(256) void k_scan_final(const int* __restrict__ deg,
                                                    const int* __restrict__ boff,
                                                    int* __restrict__ rowptr,
                                                    int* __restrict__ cursor) {
    __shared__ int l[256];
    int gid = blockIdx.x * 256 + threadIdx.x;
    int tid = threadIdx.x;
    int v = (gid < NN) ? deg[gid] : 0;
    l[tid] = v;
    __syncthreads();
    for (int d = 1; d < 256; d <<= 1) {
        int t = (tid >= d) ? l[tid - d] : 0;
        __syncthreads();
        l[tid] += t;
        __syncthreads();
    }
    int ex = l[tid] - v + boff[blockIdx.x];
    if (gid < NN) { rowptr[gid] = ex; cursor[gid] = ex; }
    if (gid == 0) rowptr[NN] = ETOT;  // total incl. self-loops is a constant
}

__global__ __launch_bounds__(256) void k_scatter(const int* __restrict__ src32,
                                                 const int* __restrict__ dst32,
                                                 int* __restrict__ cursor,
                                                 int* __restrict__ csr_src) {
    int e = blockIdx.x * 256 + threadIdx.x;
    if (e >= ETOT) return;
    int pos = atomicAdd(&cursor[dst32[e]], 1);
    csr_src[pos] = src32[e];
}

// C[M,256] = A[M,K] @ B[K,256], fp32 tiled (round-4 proven shape: BM=64,
// BN=64=one head, BK=16, 256 thr, 4x4/thr). Output h stored FP16 interleaved:
// C16[m*256 + dim*4 + head]. Attention logits stay fp32 (computed from fp32
// accumulators in the epilogue) -- only the gathered payload is rounded.
template <int K>
__global__ __launch_bounds__(256) void k_gemm(const float* __restrict__ A,
                                              const float* __restrict__ B,
                                              const float* __restrict__ asrc,
                                              const float* __restrict__ adst,
                                              __half* __restrict__ C16,
                                              float* __restrict__ os,
                                              float* __restrict__ od, int M) {
    __shared__ float As[16][68];
    __shared__ float Bs[16][68];
    const int m0 = blockIdx.x * 64, head = blockIdx.y, n0 = head * 64;
    const int tid = threadIdx.x;
    const int tx = tid & 15, ty = tid >> 4;
    float acc[4][4] = {};
    for (int k0 = 0; k0 < K; k0 += 16) {
        {
            int c = tid & 15, r0 = tid >> 4;
#pragma unroll
            for (int rr = 0; rr < 4; ++rr) {
                int r = r0 + rr * 16, gm = m0 + r;
                As[c][r] = (gm < M) ? A[gm * K + k0 + c] : 0.f;
            }
        }
        {
            int j = tid & 63, kb = tid >> 6;
#pragma unroll
            for (int cc = 0; cc < 4; ++cc) {
                int k = kb + cc * 4;
                Bs[k][j] = B[(k0 + k) * 256 + n0 + j];
            }
        }
        __syncthreads();
#pragma unroll
        for (int k = 0; k < 16; ++k) {
            float a[4], b[4];
            *(float4*)a = *(const float4*)&As[k][ty * 4];
            *(float4*)b = *(const float4*)&Bs[k][tx * 4];
#pragma unroll
            for (int i = 0; i < 4; ++i)
#pragma unroll
                for (int j = 0; j < 4; ++j) acc[i][j] += a[i] * b[j];
        }
        __syncthreads();
    }
#pragma unroll
    for (int i = 0; i < 4; ++i) {
        int gm = m0 + ty * 4 + i;
        if (gm < M) {
#pragma unroll
            for (int j = 0; j < 4; ++j)
                C16[gm * 256 + (tx * 4 + j) * 4 + head] = __float2half(acc[i][j]);
        }
    }
    // fused alpha_s / alpha_d (fp32)
    float4 av = *(const float4*)&asrc[head * 64 + tx * 4];
    float4 dv = *(const float4*)&adst[head * 64 + tx * 4];
    float ps[4], pd[4];
#pragma unroll
    for (int i = 0; i < 4; ++i) {
        ps[i] = acc[i][0] * av.x + acc[i][1] * av.y + acc[i][2] * av.z + acc[i][3] * av.w;
        pd[i] = acc[i][0] * dv.x + acc[i][1] * dv.y + acc[i][2] * dv.z + acc[i][3] * dv.w;
    }
#pragma unroll
    for (int off = 1; off < 16; off <<= 1) {
#pragma unroll
        for (int i = 0; i < 4; ++i) {
            ps[i] += __shfl_xor(ps[i], off);
            pd[i] += __shfl_xor(pd[i], off);
        }
    }
    if (tx == 0) {
#pragma unroll
        for (int i = 0; i < 4; ++i) {
            int gm = m0 + ty * 4 + i;
            if (gm < M) {
                os[gm * 4 + head] = ps[i];
                od[gm * 4 + head] = pd[i];
            }
        }
    }
}

__device__ __forceinline__ float lrelu_exp(float x) {
    x = x > 0.f ? x : 0.2f * x;
    return __expf(x);
}

// Wave per dst node (round-4 structure; round-5's 4-wide unroll regressed --
// cross-wave MLP already saturates the fill path; kernel is bound by
// FETCH bytes, which fp16 h halves).
__global__ __launch_bounds__(256) void k_aggr(const int* __restrict__ rowptr,
                                              const int* __restrict__ csr_src,
                                              const float* __restrict__ as_,
                                              const float* __restrict__ ad_,
                                              const __half* __restrict__ h16,
                                              const float* __restrict__ bias,
                                              float* __restrict__ out) {
    int d = (blockIdx.x * 256 + threadIdx.x) >> 6;
    int lane = threadIdx.x & 63;
    if (d >= NN) return;
    int beg = rowptr[d], end = rowptr[d + 1];
    float4 adv = *(const float4*)(ad_ + d * 4);

    // pass 1: denominator + chunk-0 register cache
    int s0 = 0;
    float4 u0 = make_float4(0.f, 0.f, 0.f, 0.f);
    float4 den = make_float4(0.f, 0.f, 0.f, 0.f);
    int i0 = beg + lane;
    if (i0 < end) {
        s0 = csr_src[i0];
        float4 sv = *(const float4*)(as_ + s0 * 4);
        u0.x = lrelu_exp(sv.x + adv.x);
        u0.y = lrelu_exp(sv.y + adv.y);
        u0.z = lrelu_exp(sv.z + adv.z);
        u0.w = lrelu_exp(sv.w + adv.w);
        den = u0;
    }
    for (int i = i0 + 64; i < end; i += 64) {
        int s = csr_src[i];
        float4 sv = *(const float4*)(as_ + s * 4);
        den.x += lrelu_exp(sv.x + adv.x);
        den.y += lrelu_exp(sv.y + adv.y);
        den.z += lrelu_exp(sv.z + adv.z);
        den.w += lrelu_exp(sv.w + adv.w);
    }
#pragma unroll
    for (int off = 32; off > 0; off >>= 1) {
        den.x += __shfl_xor(den.x, off);
        den.y += __shfl_xor(den.y, off);
        den.z += __shfl_xor(den.z, off);
        den.w += __shfl_xor(den.w, off);
    }
    float4 dinv = make_float4(0.25f / den.x, 0.25f / den.y,
                              0.25f / den.z, 0.25f / den.w);

    // pass 2: chunk 0 from registers
    float acc = 0.f;
    {
        float4 al = make_float4(u0.x * dinv.x, u0.y * dinv.y,
                                u0.z * dinv.z, u0.w * dinv.w);
        int cnt = end - beg;
        if (cnt > 64) cnt = 64;
        for (int j = 0; j < cnt; ++j) {
            int sj = __shfl(s0, j);
            float a0 = __shfl(al.x, j), a1 = __shfl(al.y, j);
            float a2 = __shfl(al.z, j), a3 = __shfl(al.w, j);
            uint2 raw = *(const uint2*)(h16 + sj * 256 + lane * 4);
            float2 fa = __half22float2(*(const __half2*)&raw.x);
            float2 fb = __half22float2(*(const __half2*)&raw.y);
            acc += a0 * fa.x + a1 * fa.y + a2 * fb.x + a3 * fb.y;
        }
    }
    // rare chunks >= 1: recompute
    for (int chunk = beg + 64; chunk < end; chunk += 64) {
        int i = chunk + lane;
        int s = 0;
        float4 al = make_float4(0.f, 0.f, 0.f, 0.f);
        if (i < end) {
            s = csr_src[i];
            float4 sv = *(const float4*)(as_ + s * 4);
            al.x = lrelu_exp(sv.x + adv.x) * dinv.x;
            al.y = lrelu_exp(sv.y + adv.y) * dinv.y;
            al.z = lrelu_exp(sv.z + adv.z) * dinv.z;
            al.w = lrelu_exp(sv.w + adv.w) * dinv.w;
        }
        int cnt = end - chunk;
        if (cnt > 64) cnt = 64;
        for (int j = 0; j < cnt; ++j) {
            int sj = __shfl(s, j);
            float a0 = __shfl(al.x, j), a1 = __shfl(al.y, j);
            float a2 = __shfl(al.z, j), a3 = __shfl(al.w, j);
            uint2 raw = *(const uint2*)(h16 + sj * 256 + lane * 4);
            float2 fa = __half22float2(*(const __half2*)&raw.x);
            float2 fb = __half22float2(*(const __half2*)&raw.y);
            acc += a0 * fa.x + a1 * fa.y + a2 * fb.x + a3 * fb.y;
        }
    }
    float v = acc + bias[lane];
    out[d * 64 + lane] = v > 0.f ? v : 0.f;
}

// batch is SORTED: binary-search the node range per graph -> no atomics.
__global__ __launch_bounds__(64) void k_pool_fc(const float* __restrict__ x3,
                                                const int* __restrict__ batch,
                                                const int* __restrict__ flag,
                                                const float* __restrict__ fcW,
                                                const float* __restrict__ fcb,
                                                float* __restrict__ out) {
    int g = blockIdx.x;
    int d = threadIdx.x;  // 64
    int st = *flag;
    int lo = 0, hi = NN;
    while (lo < hi) { int mid = (lo + hi) >> 1; if (batch[(size_t)st * mid] < g) lo = mid + 1; else hi = mid; }
    int start = lo;
    hi = NN;
    while (lo < hi) { int mid = (lo + hi) >> 1; if (batch[(size_t)st * mid] < g + 1) lo = mid + 1; else hi = mid; }
    int end = lo;
    float sum = 0.f;
    for (int n = start; n < end; ++n) sum += x3[n * 64 + d];
    float c = (float)(end - start);
    if (c < 1.f) c = 1.f;
    float p = sum / c;
#pragma unroll
    for (int o = 0; o < 16; ++o) {
        float v = p * fcW[d * 16 + o];
#pragma unroll
        for (int off = 32; off > 0; off >>= 1) v += __shfl_down(v, off);
        if (d == 0) out[g * 16 + o] = v + fcb[o];
    }
}

extern "C" void kernel_launch(void* const* d_in, const int* in_sizes, int n_in,
                              void* d_out, int out_size, void* d_ws, size_t ws_size,
                              hipStream_t stream) {
    const float* x   = (const float*)d_in[0];
    const int*   ei  = (const int*)d_in[1];
    const int*   bat = (const int*)d_in[2];
    const float* W1  = (const float*)d_in[3];
    const float* a1s = (const float*)d_in[4];
    const float* a1d = (const float*)d_in[5];
    const float* b1  = (const float*)d_in[6];
    const float* W2  = (const float*)d_in[7];
    const float* a2s = (const float*)d_in[8];
    const float* a2d = (const float*)d_in[9];
    const float* b2  = (const float*)d_in[10];
    const float* fcW = (const float*)d_in[11];
    const float* fcb = (const float*)d_in[12];
    float* out = (float*)d_out;

    float* ws = (float*)d_ws;
    int* flag = (int*)d_ws;                       // [1] (+pad to 256)
    __half* h16  = (__half*)(ws + 256);           // [N,256] fp16 interleaved [n][dim][head]
    float* as_   = (float*)(h16 + (size_t)NN * 256);  // [N,4]
    float* ad_   = as_ + NN * 4;                  // [N,4]
    float* xacc  = ad_ + NN * 4;                  // [N,64]
    int* src32   = (int*)(xacc + (size_t)NN * 64);// [E]
    int* dst32   = src32 + ETOT;                  // [E]
    int* deg     = dst32 + ETOT;                  // [N]
    int* rowptr  = deg + NN;                      // [N+1]
    int* cursor  = rowptr + NN + 1;               // [N]
    int* csr_src = cursor + NN;                   // [E]
    int* bsum    = csr_src + ETOT;                // [NBLK]
    int* boff    = bsum + NBLK;                   // [NBLK]

    const int eb = (ETOT + 255) / 256;    // 3321
    const int wb = (NN * 64 + 255) / 256; // 12500 (wave-per-node blocks)

    // ---- one-time per call: indices + dst-CSR ----
    k_detect<<<1, 64, 0, stream>>>(ei, flag);
    k_prep<<<eb, 256, 0, stream>>>(ei, flag, src32, dst32);
    k_zero_deg<<<(NN + 255) / 256, 256, 0, stream>>>(deg);
    k_hist<<<eb, 256, 0, stream>>>(dst32, deg);
    k_blocksum<<<NBLK, 256, 0, stream>>>(deg, bsum);
    k_scan_bsum<<<1, 256, 0, stream>>>(bsum, boff);
    k_scan_final<<<NBLK, 256, 0, stream>>>(deg, boff, rowptr, cursor);
    k_scatter<<<eb, 256, 0, stream>>>(src32, dst32, cursor, csr_src);

    const dim3 g1((NN + 63) / 64, 4);
    // ---- layer 1 ----
    k_gemm<128><<<g1, 256, 0, stream>>>(x, W1, a1s, a1d, h16, as_, ad_, NN);
    k_aggr<<<wb, 256, 0, stream>>>(rowptr, csr_src, as_, ad_, h16, b1, xacc);
    // ---- layer 2 ----
    k_gemm<64><<<g1, 256, 0, stream>>>(xacc, W2, a2s, a2d, h16, as_, ad_, NN);
    k_aggr<<<wb, 256, 0, stream>>>(rowptr, csr_src, as_, ad_, h16, b2, xacc);
    // ---- pool + fc ----
    k_pool_fc<<<NG, 64, 0, stream>>>(xacc, bat, flag, fcW, fcb, out);
}

// Round 7
// 478.263 us; speedup vs baseline: 1.4499x; 1.0984x over previous
//
#include <hip/hip_runtime.h>
#include <hip/hip_bf16.h>
#include <hip/hip_fp16.h>

#define NN 50000
#define EE 800000
#define ETOT 850000
#define NG 500
#define NBLK ((NN + 255) / 256)  // 196 scan blocks

// int64 vs int32 index detect: node ids < 50000, so int64 => odd words all 0.
__global__ void k_detect(const int* __restrict__ ei, int* __restrict__ flag) {
    unsigned long long b = __ballot(ei[2 * threadIdx.x + 1] != 0);
    if (threadIdx.x == 0) *flag = b ? 1 : 2;
}

// edge list (either width) -> int32 src/dst with self-loops appended.
__global__ __launch_bounds__(256) void k_prep(const int* __restrict__ ei,
                                              const int* __restrict__ flag,
                                              int* __restrict__ src32,
                                              int* __restrict__ dst32) {
    int e = blockIdx.x * 256 + threadIdx.x;
    if (e >= ETOT) return;
    int st = *flag;
    if (e < EE) {
        src32[e] = ei[(size_t)st * e];
        dst32[e] = ei[(size_t)st * (EE + e)];
    } else {
        src32[e] = dst32[e] = e - EE;  // self-loop
    }
}

__global__ __launch_bounds__(256) void k_zero_deg(int* __restrict__ deg) {
    int i = blockIdx.x * 256 + threadIdx.x;
    if (i < NN) deg[i] = 0;
}

__global__ __launch_bounds__(256) void k_hist(const int* __restrict__ dst32,
                                              int* __restrict__ deg) {
    int e = blockIdx.x * 256 + threadIdx.x;
    if (e < ETOT) atomicAdd(&deg[dst32[e]], 1);
}

// ---- 3-phase multi-block exclusive scan of deg[NN] ----
__global__ __launch_bounds__(256) void k_blocksum(const int* __restrict__ deg,
                                                  int* __restrict__ bsum) {
    __shared__ int l[256];
    int gid = blockIdx.x * 256 + threadIdx.x;
    int tid = threadIdx.x;
    l[tid] = (gid < NN) ? deg[gid] : 0;
    __syncthreads();
    for (int o = 128; o > 0; o >>= 1) {
        if (tid < o) l[tid] += l[tid + o];
        __syncthreads();
    }
    if (tid == 0) bsum[blockIdx.x] = l[0];
}

__global__ __launch_bounds__(256) void k_scan_bsum(const int* __restrict__ bsum,
                                                   int* __restrict__ boff) {
    __shared__ int l[256];
    int tid = threadIdx.x;
    int v = (tid < NBLK) ? bsum[tid] : 0;
    l[tid] = v;
    __syncthreads();
    for (int d = 1; d < 256; d <<= 1) {
        int t = (tid >= d) ? l[tid - d] : 0;
        __syncthreads();
        l[tid] += t;
        __syncthreads();
    }
    if (tid < NBLK) boff[tid] = l[tid] - v;  // exclusive
}

__global__ __launch_bounds__(256) void k_scan_final(const int* __restrict__ deg,
                                                    const int* __restrict__ boff,
                                                    int* __restrict__ rowptr,
                                                    int* __restrict__ cursor) {
    __shared__ int l[256];
    int gid = blockIdx.x * 256 + threadIdx.x;
    int tid = threadIdx.x;
    int v = (gid < NN) ? deg[gid] : 0;
    l[tid] = v;
    __syncthreads();
    for (int d = 1; d < 256; d <<= 1) {
        int t = (tid >= d) ? l[tid - d] : 0;
        __syncthreads();
        l[tid] += t;
        __syncthreads();
    }
    int ex = l[tid] - v + boff[blockIdx.x];
    if (gid < NN) { rowptr[gid] = ex; cursor[gid] = ex; }
    if (gid == 0) rowptr[NN] = ETOT;  // total incl. self-loops is a constant
}

__global__ __launch_bounds__(256) void k_scatter(const int* __restrict__ src32,
                                                 const int* __restrict__ dst32,
                                                 int* __restrict__ cursor,
                                                 int* __restrict__ csr_src) {
    int e = blockIdx.x * 256 + threadIdx.x;
    if (e >= ETOT) return;
    int pos = atomicAdd(&cursor[dst32[e]], 1);
    csr_src[pos] = src32[e];
}

// C[M,256] = A[M,K] @ B[K,256], fp32 tiled. BM=64, BN=64 (one head), BK=16,
// 256 thr, 4x4/thr. h16 layout [n][head][dim]: each thread stores 4 CONTIGUOUS
// halves (one 8B store -> no write amplification; r6 interleaved layout
// cost 4x WRITE_SIZE). Heads-fastest grid: blockIdx.x = head so the 4 blocks
// sharing an A-tile are dispatched back-to-back (L2 reuse on x).
template <int K>
__global__ __launch_bounds__(256) void k_gemm(const float* __restrict__ A,
                                              const float* __restrict__ B,
                                              const float* __restrict__ asrc,
                                              const float* __restrict__ adst,
                                              __half* __restrict__ C16,
                                              float* __restrict__ os,
                                              float* __restrict__ od, int M) {
    __shared__ float As[16][68];
    __shared__ float Bs[16][68];
    const int head = blockIdx.x, m0 = blockIdx.y * 64, n0 = head * 64;
    const int tid = threadIdx.x;
    const int tx = tid & 15, ty = tid >> 4;
    float acc[4][4] = {};
    for (int k0 = 0; k0 < K; k0 += 16) {
        {
            int c = tid & 15, r0 = tid >> 4;
#pragma unroll
            for (int rr = 0; rr < 4; ++rr) {
                int r = r0 + rr * 16, gm = m0 + r;
                As[c][r] = (gm < M) ? A[gm * K + k0 + c] : 0.f;
            }
        }
        {
            int j = tid & 63, kb = tid >> 6;
#pragma unroll
            for (int cc = 0; cc < 4; ++cc) {
                int k = kb + cc * 4;
                Bs[k][j] = B[(k0 + k) * 256 + n0 + j];
            }
        }
        __syncthreads();
#pragma unroll
        for (int k = 0; k < 16; ++k) {
            float a[4], b[4];
            *(float4*)a = *(const float4*)&As[k][ty * 4];
            *(float4*)b = *(const float4*)&Bs[k][tx * 4];
#pragma unroll
            for (int i = 0; i < 4; ++i)
#pragma unroll
                for (int j = 0; j < 4; ++j) acc[i][j] += a[i] * b[j];
        }
        __syncthreads();
    }
    // contiguous fp16 store: [n][head][dim], thread owns dims tx*4..tx*4+3
#pragma unroll
    for (int i = 0; i < 4; ++i) {
        int gm = m0 + ty * 4 + i;
        if (gm < M) {
            __half2 p0 = __floats2half2_rn(acc[i][0], acc[i][1]);
            __half2 p1 = __floats2half2_rn(acc[i][2], acc[i][3]);
            uint2 pk;
            pk.x = *(unsigned*)&p0;
            pk.y = *(unsigned*)&p1;
            *(uint2*)(C16 + gm * 256 + head * 64 + tx * 4) = pk;
        }
    }
    // fused alpha_s / alpha_d (fp32)
    float4 av = *(const float4*)&asrc[head * 64 + tx * 4];
    float4 dv = *(const float4*)&adst[head * 64 + tx * 4];
    float ps[4], pd[4];
#pragma unroll
    for (int i = 0; i < 4; ++i) {
        ps[i] = acc[i][0] * av.x + acc[i][1] * av.y + acc[i][2] * av.z + acc[i][3] * av.w;
        pd[i] = acc[i][0] * dv.x + acc[i][1] * dv.y + acc[i][2] * dv.z + acc[i][3] * dv.w;
    }
#pragma unroll
    for (int off = 1; off < 16; off <<= 1) {
#pragma unroll
        for (int i = 0; i < 4; ++i) {
            ps[i] += __shfl_xor(ps[i], off);
            pd[i] += __shfl_xor(pd[i], off);
        }
    }
    if (tx == 0) {
#pragma unroll
        for (int i = 0; i < 4; ++i) {
            int gm = m0 + ty * 4 + i;
            if (gm < M) {
                os[gm * 4 + head] = ps[i];
                od[gm * 4 + head] = pd[i];
            }
        }
    }
}

__device__ __forceinline__ float lrelu_exp(float x) {
    x = x > 0.f ? x : 0.2f * x;
    return __expf(x);
}

// Wave per dst node. h16 is [n][head][dim]; lane=dim reads 4 coalesced 2B
// loads (offsets 0/64/128/192) -- same gathered bytes as one 8B load, and
// lets the GEMM store contiguously.
__global__ __launch_bounds__(256) void k_aggr(const int* __restrict__ rowptr,
                                              const int* __restrict__ csr_src,
                                              const float* __restrict__ as_,
                                              const float* __restrict__ ad_,
                                              const __half* __restrict__ h16,
                                              const float* __restrict__ bias,
                                              float* __restrict__ out) {
    int d = (blockIdx.x * 256 + threadIdx.x) >> 6;
    int lane = threadIdx.x & 63;
    if (d >= NN) return;
    int beg = rowptr[d], end = rowptr[d + 1];
    float4 adv = *(const float4*)(ad_ + d * 4);

    // pass 1: denominator + chunk-0 register cache
    int s0 = 0;
    float4 u0 = make_float4(0.f, 0.f, 0.f, 0.f);
    float4 den = make_float4(0.f, 0.f, 0.f, 0.f);
    int i0 = beg + lane;
    if (i0 < end) {
        s0 = csr_src[i0];
        float4 sv = *(const float4*)(as_ + s0 * 4);
        u0.x = lrelu_exp(sv.x + adv.x);
        u0.y = lrelu_exp(sv.y + adv.y);
        u0.z = lrelu_exp(sv.z + adv.z);
        u0.w = lrelu_exp(sv.w + adv.w);
        den = u0;
    }
    for (int i = i0 + 64; i < end; i += 64) {
        int s = csr_src[i];
        float4 sv = *(const float4*)(as_ + s * 4);
        den.x += lrelu_exp(sv.x + adv.x);
        den.y += lrelu_exp(sv.y + adv.y);
        den.z += lrelu_exp(sv.z + adv.z);
        den.w += lrelu_exp(sv.w + adv.w);
    }
#pragma unroll
    for (int off = 32; off > 0; off >>= 1) {
        den.x += __shfl_xor(den.x, off);
        den.y += __shfl_xor(den.y, off);
        den.z += __shfl_xor(den.z, off);
        den.w += __shfl_xor(den.w, off);
    }
    float4 dinv = make_float4(0.25f / den.x, 0.25f / den.y,
                              0.25f / den.z, 0.25f / den.w);

    // pass 2: chunk 0 from registers
    float acc = 0.f;
    {
        float4 al = make_float4(u0.x * dinv.x, u0.y * dinv.y,
                                u0.z * dinv.z, u0.w * dinv.w);
        int cnt = end - beg;
        if (cnt > 64) cnt = 64;
        for (int j = 0; j < cnt; ++j) {
            int sj = __shfl(s0, j);
            float a0 = __shfl(al.x, j), a1 = __shfl(al.y, j);
            float a2 = __shfl(al.z, j), a3 = __shfl(al.w, j);
            const __half* hp = h16 + sj * 256 + lane;
            acc += a0 * __half2float(hp[0])   + a1 * __half2float(hp[64]) +
                   a2 * __half2float(hp[128]) + a3 * __half2float(hp[192]);
        }
    }
    // rare chunks >= 1: recompute
    for (int chunk = beg + 64; chunk < end; chunk += 64) {
        int i = chunk + lane;
        int s = 0;
        float4 al = make_float4(0.f, 0.f, 0.f, 0.f);
        if (i < end) {
            s = csr_src[i];
            float4 sv = *(const float4*)(as_ + s * 4);
            al.x = lrelu_exp(sv.x + adv.x) * dinv.x;
            al.y = lrelu_exp(sv.y + adv.y) * dinv.y;
            al.z = lrelu_exp(sv.z + adv.z) * dinv.z;
            al.w = lrelu_exp(sv.w + adv.w) * dinv.w;
        }
        int cnt = end - chunk;
        if (cnt > 64) cnt = 64;
        for (int j = 0; j < cnt; ++j) {
            int sj = __shfl(s, j);
            float a0 = __shfl(al.x, j), a1 = __shfl(al.y, j);
            float a2 = __shfl(al.z, j), a3 = __shfl(al.w, j);
            const __half* hp = h16 + sj * 256 + lane;
            acc += a0 * __half2float(hp[0])   + a1 * __half2float(hp[64]) +
                   a2 * __half2float(hp[128]) + a3 * __half2float(hp[192]);
        }
    }
    float v = acc + bias[lane];
    out[d * 64 + lane] = v > 0.f ? v : 0.f;
}

// batch is SORTED: binary-search the node range per graph -> no atomics.
__global__ __launch_bounds__(64) void k_pool_fc(const float* __restrict__ x3,
                                                const int* __restrict__ batch,
                                                const int* __restrict__ flag,
                                                const float* __restrict__ fcW,
                                                const float* __restrict__ fcb,
                                                float* __restrict__ out) {
    int g = blockIdx.x;
    int d = threadIdx.x;  // 64
    int st = *flag;
    int lo = 0, hi = NN;
    while (lo < hi) { int mid = (lo + hi) >> 1; if (batch[(size_t)st * mid] < g) lo = mid + 1; else hi = mid; }
    int start = lo;
    hi = NN;
    while (lo < hi) { int mid = (lo + hi) >> 1; if (batch[(size_t)st * mid] < g + 1) lo = mid + 1; else hi = mid; }
    int end = lo;
    float sum = 0.f;
    for (int n = start; n < end; ++n) sum += x3[n * 64 + d];
    float c = (float)(end - start);
    if (c < 1.f) c = 1.f;
    float p = sum / c;
#pragma unroll
    for (int o = 0; o < 16; ++o) {
        float v = p * fcW[d * 16 + o];
#pragma unroll
        for (int off = 32; off > 0; off >>= 1) v += __shfl_down(v, off);
        if (d == 0) out[g * 16 + o] = v + fcb[o];
    }
}

extern "C" void kernel_launch(void* const* d_in, const int* in_sizes, int n_in,
                              void* d_out, int out_size, void* d_ws, size_t ws_size,
                              hipStream_t stream) {
    const float* x   = (const float*)d_in[0];
    const int*   ei  = (const int*)d_in[1];
    const int*   bat = (const int*)d_in[2];
    const float* W1  = (const float*)d_in[3];
    const float* a1s = (const float*)d_in[4];
    const float* a1d = (const float*)d_in[5];
    const float* b1  = (const float*)d_in[6];
    const float* W2  = (const float*)d_in[7];
    const float* a2s = (const float*)d_in[8];
    const float* a2d = (const float*)d_in[9];
    const float* b2  = (const float*)d_in[10];
    const float* fcW = (const float*)d_in[11];
    const float* fcb = (const float*)d_in[12];
    float* out = (float*)d_out;

    float* ws = (float*)d_ws;
    int* flag = (int*)d_ws;                       // [1] (+pad to 256)
    __half* h16  = (__half*)(ws + 256);           // [N,256] fp16 [n][head][dim]
    float* as_   = (float*)(h16 + (size_t)NN * 256);  // [N,4]
    float* ad_   = as_ + NN * 4;                  // [N,4]
    float* xacc  = ad_ + NN * 4;                  // [N,64]
    int* src32   = (int*)(xacc + (size_t)NN * 64);// [E]
    int* dst32   = src32 + ETOT;                  // [E]
    int* deg     = dst32 + ETOT;                  // [N]
    int* rowptr  = deg + NN;                      // [N+1]
    int* cursor  = rowptr + NN + 1;               // [N]
    int* csr_src = cursor + NN;                   // [E]
    int* bsum    = csr_src + ETOT;                // [NBLK]
    int* boff    = bsum + NBLK;                   // [NBLK]

    const int eb = (ETOT + 255) / 256;    // 3321
    const int wb = (NN * 64 + 255) / 256; // 12500 (wave-per-node blocks)

    // ---- one-time per call: indices + dst-CSR ----
    k_detect<<<1, 64, 0, stream>>>(ei, flag);
    k_prep<<<eb, 256, 0, stream>>>(ei, flag, src32, dst32);
    k_zero_deg<<<(NN + 255) / 256, 256, 0, stream>>>(deg);
    k_hist<<<eb, 256, 0, stream>>>(dst32, deg);
    k_blocksum<<<NBLK, 256, 0, stream>>>(deg, bsum);
    k_scan_bsum<<<1, 256, 0, stream>>>(bsum, boff);
    k_scan_final<<<NBLK, 256, 0, stream>>>(deg, boff, rowptr, cursor);
    k_scatter<<<eb, 256, 0, stream>>>(src32, dst32, cursor, csr_src);

    const dim3 g1(4, (NN + 63) / 64);  // heads fastest -> A-tile L2 reuse
    // ---- layer 1 ----
    k_gemm<128><<<g1, 256, 0, stream>>>(x, W1, a1s, a1d, h16, as_, ad_, NN);
    k_aggr<<<wb, 256, 0, stream>>>(rowptr, csr_src, as_, ad_, h16, b1, xacc);
    // ---- layer 2 ----
    k_gemm<64><<<g1, 256, 0, stream>>>(xacc, W2, a2s, a2d, h16, as_, ad_, NN);
    k_aggr<<<wb, 256, 0, stream>>>(rowptr, csr_src, as_, ad_, h16, b2, xacc);
    // ---- pool + fc ----
    k_pool_fc<<<NG, 64, 0, stream>>>(xacc, bat, flag, fcW, fcb, out);
}

// Round 8
// 470.709 us; speedup vs baseline: 1.4732x; 1.0160x over previous
//
#include <hip/hip_runtime.h>
#include <hip/hip_bf16.h>
#include <hip/hip_fp16.h>

#define NN 50000
#define EE 800000
#define ETOT 850000
#define NG 500
#define NBLK ((NN + 255) / 256)  // 196 scan blocks

// int64 vs int32 index detect: node ids < 50000, so int64 => odd words all 0.
__global__ void k_detect(const int* __restrict__ ei, int* __restrict__ flag) {
    unsigned long long b = __ballot(ei[2 * threadIdx.x + 1] != 0);
    if (threadIdx.x == 0) *flag = b ? 1 : 2;
}

// edge list -> int32 src/dst with self-loops appended; fused degree histogram.
__global__ __launch_bounds__(256) void k_prep(const int* __restrict__ ei,
                                              const int* __restrict__ flag,
                                              int* __restrict__ src32,
                                              int* __restrict__ dst32,
                                              int* __restrict__ deg) {
    int e = blockIdx.x * 256 + threadIdx.x;
    if (e >= ETOT) return;
    int st = *flag;
    int s, d;
    if (e < EE) {
        s = ei[(size_t)st * e];
        d = ei[(size_t)st * (EE + e)];
    } else {
        s = d = e - EE;  // self-loop
    }
    src32[e] = s;
    dst32[e] = d;
    atomicAdd(&deg[d], 1);
}

// ---- 3-phase multi-block exclusive scan of deg[NN] ----
__global__ __launch_bounds__(256) void k_blocksum(const int* __restrict__ deg,
                                                  int* __restrict__ bsum) {
    __shared__ int l[256];
    int gid = blockIdx.x * 256 + threadIdx.x;
    int tid = threadIdx.x;
    l[tid] = (gid < NN) ? deg[gid] : 0;
    __syncthreads();
    for (int o = 128; o > 0; o >>= 1) {
        if (tid < o) l[tid] += l[tid + o];
        __syncthreads();
    }
    if (tid == 0) bsum[blockIdx.x] = l[0];
}

__global__ __launch_bounds__(256) void k_scan_bsum(const int* __restrict__ bsum,
                                                   int* __restrict__ boff) {
    __shared__ int l[256];
    int tid = threadIdx.x;
    int v = (tid < NBLK) ? bsum[tid] : 0;
    l[tid] = v;
    __syncthreads();
    for (int d = 1; d < 256; d <<= 1) {
        int t = (tid >= d) ? l[tid - d] : 0;
        __syncthreads();
        l[tid] += t;
        __syncthreads();
    }
    if (tid < NBLK) boff[tid] = l[tid] - v;  // exclusive
}

__global__ __launch_bounds__(256) void k_scan_final(const int* __restrict__ deg,
                                                    const int* __restrict__ boff,
                                                    int* __restrict__ rowptr,
                                                    int* __restrict__ cursor) {
    __shared__ int l[256];
    int gid = blockIdx.x * 256 + threadIdx.x;
    int tid = threadIdx.x;
    int v = (gid < NN) ? deg[gid] : 0;
    l[tid] = v;
    __syncthreads();
    for (int d = 1; d < 256; d <<= 1) {
        int t = (tid >= d) ? l[tid - d] : 0;
        __syncthreads();
        l[tid] += t;
        __syncthreads();
    }
    int ex = l[tid] - v + boff[blockIdx.x];
    if (gid < NN) { rowptr[gid] = ex; cursor[gid] = ex; }
    if (gid == 0) rowptr[NN] = ETOT;  // total incl. self-loops is a constant
}

__global__ __launch_bounds__(256) void k_scatter(const int* __restrict__ src32,
                                                 const int* __restrict__ dst32,
                                                 int* __restrict__ cursor,
                                                 int* __restrict__ csr_src) {
    int e = blockIdx.x * 256 + threadIdx.x;
    if (e >= ETOT) return;
    int pos = atomicAdd(&cursor[dst32[e]], 1);
    csr_src[pos] = src32[e];
}

// C[M,256] = A[M,K] @ B[K,256]. ONE block = all 4 heads: BM=64, BN=256, BK=16,
// 256 thr; thread owns 4 rows x (4 dims x 4 heads). B read as 4 per-head b128
// from natural-layout LDS (2-way bank aliasing only -> free); register 4x4
// transpose at epilogue -> 16 CONTIGUOUS fp16 halves per row store:
// h16[n][dim][head] (what k_aggr's single 8B gather wants). Fused alpha
// epilogue with float4 os/od stores.
template <int K>
__global__ __launch_bounds__(256) void k_gemm(const float* __restrict__ A,
                                              const float* __restrict__ B,
                                              const float* __restrict__ asrc,
                                              const float* __restrict__ adst,
                                              __half* __restrict__ C16,
                                              float* __restrict__ os,
                                              float* __restrict__ od, int M) {
    __shared__ float As[16][68];
    __shared__ float Bs[16][260];
    const int m0 = blockIdx.x * 64;
    const int tid = threadIdx.x;
    const int tx = tid & 15, ty = tid >> 4;  // tx: dim-group, ty: row-group
    float acc[4][16] = {};  // acc[i][h*4+jd]: row ty*4+i, col h*64+tx*4+jd
    for (int k0 = 0; k0 < K; k0 += 16) {
        {   // A tile: 64 rows x 16 k
            int c = tid & 15, r0 = tid >> 4;
#pragma unroll
            for (int rr = 0; rr < 4; ++rr) {
                int r = r0 + rr * 16, gm = m0 + r;
                As[c][r] = (gm < M) ? A[gm * K + k0 + c] : 0.f;
            }
        }
        {   // B tile: 16 k x 256 n (natural layout, coalesced)
#pragma unroll
            for (int kk = 0; kk < 16; ++kk)
                Bs[kk][tid] = B[(k0 + kk) * 256 + tid];
        }
        __syncthreads();
#pragma unroll
        for (int k = 0; k < 16; ++k) {
            float a[4], b[16];
            *(float4*)a = *(const float4*)&As[k][ty * 4];
#pragma unroll
            for (int h = 0; h < 4; ++h)
                *(float4*)&b[h * 4] = *(const float4*)&Bs[k][h * 64 + tx * 4];
#pragma unroll
            for (int i = 0; i < 4; ++i)
#pragma unroll
                for (int j = 0; j < 16; ++j) acc[i][j] += a[i] * b[j];
        }
        __syncthreads();
    }
    // interleaved fp16 store: memory index (tx*4+jd)*4+h = tx*16 + jd*4 + h
#pragma unroll
    for (int i = 0; i < 4; ++i) {
        int gm = m0 + ty * 4 + i;
        if (gm < M) {
            __half hbuf[16];
#pragma unroll
            for (int jd = 0; jd < 4; ++jd) {
                __half2 p0 = __floats2half2_rn(acc[i][0 * 4 + jd], acc[i][1 * 4 + jd]);
                __half2 p1 = __floats2half2_rn(acc[i][2 * 4 + jd], acc[i][3 * 4 + jd]);
                *(__half2*)&hbuf[jd * 4]     = p0;
                *(__half2*)&hbuf[jd * 4 + 2] = p1;
            }
            *(uint4*)(C16 + gm * 256 + tx * 16)     = *(uint4*)&hbuf[0];
            *(uint4*)(C16 + gm * 256 + tx * 16 + 8) = *(uint4*)&hbuf[8];
        }
    }
    // fused alpha_s / alpha_d (fp32), all 4 heads in-thread
    float ps[4][4], pd[4][4];  // [row][head]
#pragma unroll
    for (int h = 0; h < 4; ++h) {
        float4 av = *(const float4*)&asrc[h * 64 + tx * 4];
        float4 dv = *(const float4*)&adst[h * 64 + tx * 4];
#pragma unroll
        for (int i = 0; i < 4; ++i) {
            ps[i][h] = acc[i][h * 4 + 0] * av.x + acc[i][h * 4 + 1] * av.y +
                       acc[i][h * 4 + 2] * av.z + acc[i][h * 4 + 3] * av.w;
            pd[i][h] = acc[i][h * 4 + 0] * dv.x + acc[i][h * 4 + 1] * dv.y +
                       acc[i][h * 4 + 2] * dv.z + acc[i][h * 4 + 3] * dv.w;
        }
    }
#pragma unroll
    for (int off = 1; off < 16; off <<= 1) {
#pragma unroll
        for (int i = 0; i < 4; ++i)
#pragma unroll
            for (int h = 0; h < 4; ++h) {
                ps[i][h] += __shfl_xor(ps[i][h], off);
                pd[i][h] += __shfl_xor(pd[i][h], off);
            }
    }
    if (tx == 0) {
#pragma unroll
        for (int i = 0; i < 4; ++i) {
            int gm = m0 + ty * 4 + i;
            if (gm < M) {
                *(float4*)(os + gm * 4) = make_float4(ps[i][0], ps[i][1], ps[i][2], ps[i][3]);
                *(float4*)(od + gm * 4) = make_float4(pd[i][0], pd[i][1], pd[i][2], pd[i][3]);
            }
        }
    }
}

__device__ __forceinline__ float lrelu_exp(float x) {
    x = x > 0.f ? x : 0.2f * x;
    return __expf(x);
}

// Wave per dst node. h16 [n][dim][head]: lane=dim -> ONE 8B load + 2 packed
// cvt per edge (r7's 4x2B scalar loads throttled the memory pipeline).
__global__ __launch_bounds__(256) void k_aggr(const int* __restrict__ rowptr,
                                              const int* __restrict__ csr_src,
                                              const float* __restrict__ as_,
                                              const float* __restrict__ ad_,
                                              const __half* __restrict__ h16,
                                              const float* __restrict__ bias,
                                              float* __restrict__ out) {
    int d = (blockIdx.x * 256 + threadIdx.x) >> 6;
    int lane = threadIdx.x & 63;
    if (d >= NN) return;
    int beg = rowptr[d], end = rowptr[d + 1];
    float4 adv = *(const float4*)(ad_ + d * 4);

    // pass 1: denominator + chunk-0 register cache
    int s0 = 0;
    float4 u0 = make_float4(0.f, 0.f, 0.f, 0.f);
    float4 den = make_float4(0.f, 0.f, 0.f, 0.f);
    int i0 = beg + lane;
    if (i0 < end) {
        s0 = csr_src[i0];
        float4 sv = *(const float4*)(as_ + s0 * 4);
        u0.x = lrelu_exp(sv.x + adv.x);
        u0.y = lrelu_exp(sv.y + adv.y);
        u0.z = lrelu_exp(sv.z + adv.z);
        u0.w = lrelu_exp(sv.w + adv.w);
        den = u0;
    }
    for (int i = i0 + 64; i < end; i += 64) {
        int s = csr_src[i];
        float4 sv = *(const float4*)(as_ + s * 4);
        den.x += lrelu_exp(sv.x + adv.x);
        den.y += lrelu_exp(sv.y + adv.y);
        den.z += lrelu_exp(sv.z + adv.z);
        den.w += lrelu_exp(sv.w + adv.w);
    }
#pragma unroll
    for (int off = 32; off > 0; off >>= 1) {
        den.x += __shfl_xor(den.x, off);
        den.y += __shfl_xor(den.y, off);
        den.z += __shfl_xor(den.z, off);
        den.w += __shfl_xor(den.w, off);
    }
    float4 dinv = make_float4(0.25f / den.x, 0.25f / den.y,
                              0.25f / den.z, 0.25f / den.w);

    // pass 2: chunk 0 from registers
    float acc = 0.f;
    {
        float4 al = make_float4(u0.x * dinv.x, u0.y * dinv.y,
                                u0.z * dinv.z, u0.w * dinv.w);
        int cnt = end - beg;
        if (cnt > 64) cnt = 64;
        for (int j = 0; j < cnt; ++j) {
            int sj = __shfl(s0, j);
            float a0 = __shfl(al.x, j), a1 = __shfl(al.y, j);
            float a2 = __shfl(al.z, j), a3 = __shfl(al.w, j);
            uint2 raw = *(const uint2*)(h16 + sj * 256 + lane * 4);
            float2 fa = __half22float2(*(const __half2*)&raw.x);
            float2 fb = __half22float2(*(const __half2*)&raw.y);
            acc += a0 * fa.x + a1 * fa.y + a2 * fb.x + a3 * fb.y;
        }
    }
    // rare chunks >= 1: recompute
    for (int chunk = beg + 64; chunk < end; chunk += 64) {
        int i = chunk + lane;
        int s = 0;
        float4 al = make_float4(0.f, 0.f, 0.f, 0.f);
        if (i < end) {
            s = csr_src[i];
            float4 sv = *(const float4*)(as_ + s * 4);
            al.x = lrelu_exp(sv.x + adv.x) * dinv.x;
            al.y = lrelu_exp(sv.y + adv.y) * dinv.y;
            al.z = lrelu_exp(sv.z + adv.z) * dinv.z;
            al.w = lrelu_exp(sv.w + adv.w) * dinv.w;
        }
        int cnt = end - chunk;
        if (cnt > 64) cnt = 64;
        for (int j = 0; j < cnt; ++j) {
            int sj = __shfl(s, j);
            float a0 = __shfl(al.x, j), a1 = __shfl(al.y, j);
            float a2 = __shfl(al.z, j), a3 = __shfl(al.w, j);
            uint2 raw = *(const uint2*)(h16 + sj * 256 + lane * 4);
            float2 fa = __half22float2(*(const __half2*)&raw.x);
            float2 fb = __half22float2(*(const __half2*)&raw.y);
            acc += a0 * fa.x + a1 * fa.y + a2 * fb.x + a3 * fb.y;
        }
    }
    float v = acc + bias[lane];
    out[d * 64 + lane] = v > 0.f ? v : 0.f;
}

// batch is SORTED: binary-search the node range per graph. 4 waves split the
// node loop (was latency-bound serial at 64 threads).
__global__ __launch_bounds__(256) void k_pool_fc(const float* __restrict__ x3,
                                                 const int* __restrict__ batch,
                                                 const int* __restrict__ flag,
                                                 const float* __restrict__ fcW,
                                                 const float* __restrict__ fcb,
                                                 float* __restrict__ out) {
    int g = blockIdx.x;
    int tid = threadIdx.x, lane = tid & 63, w = tid >> 6;
    int st = *flag;
    int lo = 0, hi = NN;
    while (lo < hi) { int mid = (lo + hi) >> 1; if (batch[(size_t)st * mid] < g) lo = mid + 1; else hi = mid; }
    int start = lo;
    hi = NN;
    while (lo < hi) { int mid = (lo + hi) >> 1; if (batch[(size_t)st * mid] < g + 1) lo = mid + 1; else hi = mid; }
    int end = lo;
    float sum = 0.f;
    for (int n = start + w; n < end; n += 4) sum += x3[n * 64 + lane];
    __shared__ float ls[4][64];
    ls[w][lane] = sum;
    __syncthreads();
    if (w == 0) {
        float c = (float)(end - start);
        if (c < 1.f) c = 1.f;
        float p = (ls[0][lane] + ls[1][lane] + ls[2][lane] + ls[3][lane]) / c;
#pragma unroll
        for (int o = 0; o < 16; ++o) {
            float v = p * fcW[lane * 16 + o];
#pragma unroll
            for (int off = 32; off > 0; off >>= 1) v += __shfl_down(v, off);
            if (lane == 0) out[g * 16 + o] = v + fcb[o];
        }
    }
}

extern "C" void kernel_launch(void* const* d_in, const int* in_sizes, int n_in,
                              void* d_out, int out_size, void* d_ws, size_t ws_size,
                              hipStream_t stream) {
    const float* x   = (const float*)d_in[0];
    const int*   ei  = (const int*)d_in[1];
    const int*   bat = (const int*)d_in[2];
    const float* W1  = (const float*)d_in[3];
    const float* a1s = (const float*)d_in[4];
    const float* a1d = (const float*)d_in[5];
    const float* b1  = (const float*)d_in[6];
    const float* W2  = (const float*)d_in[7];
    const float* a2s = (const float*)d_in[8];
    const float* a2d = (const float*)d_in[9];
    const float* b2  = (const float*)d_in[10];
    const float* fcW = (const float*)d_in[11];
    const float* fcb = (const float*)d_in[12];
    float* out = (float*)d_out;

    float* ws = (float*)d_ws;
    int* flag = (int*)d_ws;                       // [1] (+pad to 256)
    __half* h16  = (__half*)(ws + 256);           // [N,256] fp16 [n][dim][head]
    float* as_   = (float*)(h16 + (size_t)NN * 256);  // [N,4]
    float* ad_   = as_ + NN * 4;                  // [N,4]
    float* xacc  = ad_ + NN * 4;                  // [N,64]
    int* src32   = (int*)(xacc + (size_t)NN * 64);// [E]
    int* dst32   = src32 + ETOT;                  // [E]
    int* deg     = dst32 + ETOT;                  // [N]
    int* rowptr  = deg + NN;                      // [N+1]
    int* cursor  = rowptr + NN + 1;               // [N]
    int* csr_src = cursor + NN;                   // [E]
    int* bsum    = csr_src + ETOT;                // [NBLK]
    int* boff    = bsum + NBLK;                   // [NBLK]

    const int eb = (ETOT + 255) / 256;    // 3321
    const int wb = (NN * 64 + 255) / 256; // 12500 (wave-per-node blocks)

    // ---- one-time per call: indices + dst-CSR ----
    k_detect<<<1, 64, 0, stream>>>(ei, flag);
    hipMemsetAsync(deg, 0, NN * sizeof(int), stream);
    k_prep<<<eb, 256, 0, stream>>>(ei, flag, src32, dst32, deg);
    k_blocksum<<<NBLK, 256, 0, stream>>>(deg, bsum);
    k_scan_bsum<<<1, 256, 0, stream>>>(bsum, boff);
    k_scan_final<<<NBLK, 256, 0, stream>>>(deg, boff, rowptr, cursor);
    k_scatter<<<eb, 256, 0, stream>>>(src32, dst32, cursor, csr_src);

    const int gg = (NN + 63) / 64;  // 782 blocks, all 4 heads per block
    // ---- layer 1 ----
    k_gemm<128><<<gg, 256, 0, stream>>>(x, W1, a1s, a1d, h16, as_, ad_, NN);
    k_aggr<<<wb, 256, 0, stream>>>(rowptr, csr_src, as_, ad_, h16, b1, xacc);
    // ---- layer 2 ----
    k_gemm<64><<<gg, 256, 0, stream>>>(xacc, W2, a2s, a2d, h16, as_, ad_, NN);
    k_aggr<<<wb, 256, 0, stream>>>(rowptr, csr_src, as_, ad_, h16, b2, xacc);
    // ---- pool + fc ----
    k_pool_fc<<<NG, 256, 0, stream>>>(xacc, bat, flag, fcW, fcb, out);
}

// Round 9
// 457.887 us; speedup vs baseline: 1.5144x; 1.0280x over previous
//
#include <hip/hip_runtime.h>
#include <hip/hip_bf16.h>
#include <hip/hip_fp16.h>

#define NN 50000
#define EE 800000
#define ETOT 850000
#define NG 500
#define NBLK ((NN + 255) / 256)  // 196 scan blocks

// int64 vs int32 index detect: node ids < 50000, so int64 => odd words all 0.
__global__ void k_detect(const int* __restrict__ ei, int* __restrict__ flag) {
    unsigned long long b = __ballot(ei[2 * threadIdx.x + 1] != 0);
    if (threadIdx.x == 0) *flag = b ? 1 : 2;
}

// edge list -> int32 src/dst with self-loops appended; fused degree histogram.
__global__ __launch_bounds__(256) void k_prep(const int* __restrict__ ei,
                                              const int* __restrict__ flag,
                                              int* __restrict__ src32,
                                              int* __restrict__ dst32,
                                              int* __restrict__ deg) {
    int e = blockIdx.x * 256 + threadIdx.x;
    if (e >= ETOT) return;
    int st = *flag;
    int s, d;
    if (e < EE) {
        s = ei[(size_t)st * e];
        d = ei[(size_t)st * (EE + e)];
    } else {
        s = d = e - EE;  // self-loop
    }
    src32[e] = s;
    dst32[e] = d;
    atomicAdd(&deg[d], 1);
}

// ---- 3-phase multi-block exclusive scan of deg[NN] ----
__global__ __launch_bounds__(256) void k_blocksum(const int* __restrict__ deg,
                                                  int* __restrict__ bsum) {
    __shared__ int l[256];
    int gid = blockIdx.x * 256 + threadIdx.x;
    int tid = threadIdx.x;
    l[tid] = (gid < NN) ? deg[gid] : 0;
    __syncthreads();
    for (int o = 128; o > 0; o >>= 1) {
        if (tid < o) l[tid] += l[tid + o];
        __syncthreads();
    }
    if (tid == 0) bsum[blockIdx.x] = l[0];
}

__global__ __launch_bounds__(256) void k_scan_bsum(const int* __restrict__ bsum,
                                                   int* __restrict__ boff) {
    __shared__ int l[256];
    int tid = threadIdx.x;
    int v = (tid < NBLK) ? bsum[tid] : 0;
    l[tid] = v;
    __syncthreads();
    for (int d = 1; d < 256; d <<= 1) {
        int t = (tid >= d) ? l[tid - d] : 0;
        __syncthreads();
        l[tid] += t;
        __syncthreads();
    }
    if (tid < NBLK) boff[tid] = l[tid] - v;  // exclusive
}

__global__ __launch_bounds__(256) void k_scan_final(const int* __restrict__ deg,
                                                    const int* __restrict__ boff,
                                                    int* __restrict__ rowptr,
                                                    int* __restrict__ cursor) {
    __shared__ int l[256];
    int gid = blockIdx.x * 256 + threadIdx.x;
    int tid = threadIdx.x;
    int v = (gid < NN) ? deg[gid] : 0;
    l[tid] = v;
    __syncthreads();
    for (int d = 1; d < 256; d <<= 1) {
        int t = (tid >= d) ? l[tid - d] : 0;
        __syncthreads();
        l[tid] += t;
        __syncthreads();
    }
    int ex = l[tid] - v + boff[blockIdx.x];
    if (gid < NN) { rowptr[gid] = ex; cursor[gid] = ex; }
    if (gid == 0) rowptr[NN] = ETOT;  // total incl. self-loops is a constant
}

__global__ __launch_bounds__(256) void k_scatter(const int* __restrict__ src32,
                                                 const int* __restrict__ dst32,
                                                 int* __restrict__ cursor,
                                                 int* __restrict__ csr_src) {
    int e = blockIdx.x * 256 + threadIdx.x;
    if (e >= ETOT) return;
    int pos = atomicAdd(&cursor[dst32[e]], 1);
    csr_src[pos] = src32[e];
}

// C[M,256] = A[M,K] @ B[K,256]. BM=32, BN=256 (all 4 heads), BK=16, 256 thr;
// thread tile 2 rows x 16 cols (acc=32 VGPR -- r8's 4x16=64 VGPR + 782-block
// grid capped occupancy at ~12 waves/CU and stalled on barrier drains; BM=32
// doubles the grid to 1563 blocks, ~24 waves/CU). Interleaved fp16 epilogue
// (16 contiguous halves/row/thread -> zero write amplification) + fused alpha.
template <int K>
__global__ __launch_bounds__(256) void k_gemm(const float* __restrict__ A,
                                              const float* __restrict__ B,
                                              const float* __restrict__ asrc,
                                              const float* __restrict__ adst,
                                              __half* __restrict__ C16,
                                              float* __restrict__ os,
                                              float* __restrict__ od, int M) {
    __shared__ float As[16][34];   // [k][m], pad->b64 reads stay conflict-lite
    __shared__ float Bs[16][260];  // [k][n]
    const int m0 = blockIdx.x * 32;
    const int tid = threadIdx.x;
    const int tx = tid & 15, ty = tid >> 4;  // tx: dim-group, ty: 2-row group
    float acc[2][16] = {};  // acc[i][h*4+jd]: row ty*2+i, col h*64+tx*4+jd
    for (int k0 = 0; k0 < K; k0 += 16) {
        {   // A tile: 32 rows x 16 k; thread loads float2 along k
            int r = tid >> 3, c = (tid & 7) * 2;
            int gm = m0 + r;
            float2 av = (gm < M) ? *(const float2*)(A + gm * K + k0 + c)
                                 : make_float2(0.f, 0.f);
            As[c][r] = av.x;
            As[c + 1][r] = av.y;
        }
        {   // B tile: 16 k x 256 n; float4 loads (4 passes)
            int col = (tid & 63) * 4, rb = tid >> 6;
#pragma unroll
            for (int p = 0; p < 4; ++p) {
                int row = p * 4 + rb;
                *(float4*)&Bs[row][col] = *(const float4*)(B + (k0 + row) * 256 + col);
            }
        }
        __syncthreads();
#pragma unroll
        for (int k = 0; k < 16; ++k) {
            float a0 = As[k][ty * 2], a1 = As[k][ty * 2 + 1];
            float b[16];
#pragma unroll
            for (int h = 0; h < 4; ++h)
                *(float4*)&b[h * 4] = *(const float4*)&Bs[k][h * 64 + tx * 4];
#pragma unroll
            for (int j = 0; j < 16; ++j) {
                acc[0][j] += a0 * b[j];
                acc[1][j] += a1 * b[j];
            }
        }
        __syncthreads();
    }
    // interleaved fp16 store: memory index (tx*4+jd)*4+h = tx*16 + jd*4 + h
#pragma unroll
    for (int i = 0; i < 2; ++i) {
        int gm = m0 + ty * 2 + i;
        if (gm < M) {
            __half hbuf[16];
#pragma unroll
            for (int jd = 0; jd < 4; ++jd) {
                __half2 p0 = __floats2half2_rn(acc[i][0 * 4 + jd], acc[i][1 * 4 + jd]);
                __half2 p1 = __floats2half2_rn(acc[i][2 * 4 + jd], acc[i][3 * 4 + jd]);
                *(__half2*)&hbuf[jd * 4]     = p0;
                *(__half2*)&hbuf[jd * 4 + 2] = p1;
            }
            *(uint4*)(C16 + gm * 256 + tx * 16)     = *(uint4*)&hbuf[0];
            *(uint4*)(C16 + gm * 256 + tx * 16 + 8) = *(uint4*)&hbuf[8];
        }
    }
    // fused alpha_s / alpha_d (fp32), all 4 heads in-thread
    float ps[2][4], pd[2][4];  // [row][head]
#pragma unroll
    for (int h = 0; h < 4; ++h) {
        float4 av = *(const float4*)&asrc[h * 64 + tx * 4];
        float4 dv = *(const float4*)&adst[h * 64 + tx * 4];
#pragma unroll
        for (int i = 0; i < 2; ++i) {
            ps[i][h] = acc[i][h * 4 + 0] * av.x + acc[i][h * 4 + 1] * av.y +
                       acc[i][h * 4 + 2] * av.z + acc[i][h * 4 + 3] * av.w;
            pd[i][h] = acc[i][h * 4 + 0] * dv.x + acc[i][h * 4 + 1] * dv.y +
                       acc[i][h * 4 + 2] * dv.z + acc[i][h * 4 + 3] * dv.w;
        }
    }
#pragma unroll
    for (int off = 1; off < 16; off <<= 1) {
#pragma unroll
        for (int i = 0; i < 2; ++i)
#pragma unroll
            for (int h = 0; h < 4; ++h) {
                ps[i][h] += __shfl_xor(ps[i][h], off);
                pd[i][h] += __shfl_xor(pd[i][h], off);
            }
    }
    if (tx == 0) {
#pragma unroll
        for (int i = 0; i < 2; ++i) {
            int gm = m0 + ty * 2 + i;
            if (gm < M) {
                *(float4*)(os + gm * 4) = make_float4(ps[i][0], ps[i][1], ps[i][2], ps[i][3]);
                *(float4*)(od + gm * 4) = make_float4(pd[i][0], pd[i][1], pd[i][2], pd[i][3]);
            }
        }
    }
}

__device__ __forceinline__ float lrelu_exp(float x) {
    x = x > 0.f ? x : 0.2f * x;
    return __expf(x);
}

// Wave per dst node. h16 [n][dim][head]: lane=dim -> ONE 8B load + 2 packed
// cvt per edge.
__global__ __launch_bounds__(256) void k_aggr(const int* __restrict__ rowptr,
                                              const int* __restrict__ csr_src,
                                              const float* __restrict__ as_,
                                              const float* __restrict__ ad_,
                                              const __half* __restrict__ h16,
                                              const float* __restrict__ bias,
                                              float* __restrict__ out) {
    int d = (blockIdx.x * 256 + threadIdx.x) >> 6;
    int lane = threadIdx.x & 63;
    if (d >= NN) return;
    int beg = rowptr[d], end = rowptr[d + 1];
    float4 adv = *(const float4*)(ad_ + d * 4);

    // pass 1: denominator + chunk-0 register cache
    int s0 = 0;
    float4 u0 = make_float4(0.f, 0.f, 0.f, 0.f);
    float4 den = make_float4(0.f, 0.f, 0.f, 0.f);
    int i0 = beg + lane;
    if (i0 < end) {
        s0 = csr_src[i0];
        float4 sv = *(const float4*)(as_ + s0 * 4);
        u0.x = lrelu_exp(sv.x + adv.x);
        u0.y = lrelu_exp(sv.y + adv.y);
        u0.z = lrelu_exp(sv.z + adv.z);
        u0.w = lrelu_exp(sv.w + adv.w);
        den = u0;
    }
    for (int i = i0 + 64; i < end; i += 64) {
        int s = csr_src[i];
        float4 sv = *(const float4*)(as_ + s * 4);
        den.x += lrelu_exp(sv.x + adv.x);
        den.y += lrelu_exp(sv.y + adv.y);
        den.z += lrelu_exp(sv.z + adv.z);
        den.w += lrelu_exp(sv.w + adv.w);
    }
#pragma unroll
    for (int off = 32; off > 0; off >>= 1) {
        den.x += __shfl_xor(den.x, off);
        den.y += __shfl_xor(den.y, off);
        den.z += __shfl_xor(den.z, off);
        den.w += __shfl_xor(den.w, off);
    }
    float4 dinv = make_float4(0.25f / den.x, 0.25f / den.y,
                              0.25f / den.z, 0.25f / den.w);

    // pass 2: chunk 0 from registers
    float acc = 0.f;
    {
        float4 al = make_float4(u0.x * dinv.x, u0.y * dinv.y,
                                u0.z * dinv.z, u0.w * dinv.w);
        int cnt = end - beg;
        if (cnt > 64) cnt = 64;
        for (int j = 0; j < cnt; ++j) {
            int sj = __shfl(s0, j);
            float a0 = __shfl(al.x, j), a1 = __shfl(al.y, j);
            float a2 = __shfl(al.z, j), a3 = __shfl(al.w, j);
            uint2 raw = *(const uint2*)(h16 + sj * 256 + lane * 4);
            float2 fa = __half22float2(*(const __half2*)&raw.x);
            float2 fb = __half22float2(*(const __half2*)&raw.y);
            acc += a0 * fa.x + a1 * fa.y + a2 * fb.x + a3 * fb.y;
        }
    }
    // rare chunks >= 1: recompute
    for (int chunk = beg + 64; chunk < end; chunk += 64) {
        int i = chunk + lane;
        int s = 0;
        float4 al = make_float4(0.f, 0.f, 0.f, 0.f);
        if (i < end) {
            s = csr_src[i];
            float4 sv = *(const float4*)(as_ + s * 4);
            al.x = lrelu_exp(sv.x + adv.x) * dinv.x;
            al.y = lrelu_exp(sv.y + adv.y) * dinv.y;
            al.z = lrelu_exp(sv.z + adv.z) * dinv.z;
            al.w = lrelu_exp(sv.w + adv.w) * dinv.w;
        }
        int cnt = end - chunk;
        if (cnt > 64) cnt = 64;
        for (int j = 0; j < cnt; ++j) {
            int sj = __shfl(s, j);
            float a0 = __shfl(al.x, j), a1 = __shfl(al.y, j);
            float a2 = __shfl(al.z, j), a3 = __shfl(al.w, j);
            uint2 raw = *(const uint2*)(h16 + sj * 256 + lane * 4);
            float2 fa = __half22float2(*(const __half2*)&raw.x);
            float2 fb = __half22float2(*(const __half2*)&raw.y);
            acc += a0 * fa.x + a1 * fa.y + a2 * fb.x + a3 * fb.y;
        }
    }
    float v = acc + bias[lane];
    out[d * 64 + lane] = v > 0.f ? v : 0.f;
}

// batch is SORTED: binary-search the node range per graph. 4 waves split the
// node loop.
__global__ __launch_bounds__(256) void k_pool_fc(const float* __restrict__ x3,
                                                 const int* __restrict__ batch,
                                                 const int* __restrict__ flag,
                                                 const float* __restrict__ fcW,
                                                 const float* __restrict__ fcb,
                                                 float* __restrict__ out) {
    int g = blockIdx.x;
    int tid = threadIdx.x, lane = tid & 63, w = tid >> 6;
    int st = *flag;
    int lo = 0, hi = NN;
    while (lo < hi) { int mid = (lo + hi) >> 1; if (batch[(size_t)st * mid] < g) lo = mid + 1; else hi = mid; }
    int start = lo;
    hi = NN;
    while (lo < hi) { int mid = (lo + hi) >> 1; if (batch[(size_t)st * mid] < g + 1) lo = mid + 1; else hi = mid; }
    int end = lo;
    float sum = 0.f;
    for (int n = start + w; n < end; n += 4) sum += x3[n * 64 + lane];
    __shared__ float ls[4][64];
    ls[w][lane] = sum;
    __syncthreads();
    if (w == 0) {
        float c = (float)(end - start);
        if (c < 1.f) c = 1.f;
        float p = (ls[0][lane] + ls[1][lane] + ls[2][lane] + ls[3][lane]) / c;
#pragma unroll
        for (int o = 0; o < 16; ++o) {
            float v = p * fcW[lane * 16 + o];
#pragma unroll
            for (int off = 32; off > 0; off >>= 1) v += __shfl_down(v, off);
            if (lane == 0) out[g * 16 + o] = v + fcb[o];
        }
    }
}

extern "C" void kernel_launch(void* const* d_in, const int* in_sizes, int n_in,
                              void* d_out, int out_size, void* d_ws, size_t ws_size,
                              hipStream_t stream) {
    const float* x   = (const float*)d_in[0];
    const int*   ei  = (const int*)d_in[1];
    const int*   bat = (const int*)d_in[2];
    const float* W1  = (const float*)d_in[3];
    const float* a1s = (const float*)d_in[4];
    const float* a1d = (const float*)d_in[5];
    const float* b1  = (const float*)d_in[6];
    const float* W2  = (const float*)d_in[7];
    const float* a2s = (const float*)d_in[8];
    const float* a2d = (const float*)d_in[9];
    const float* b2  = (const float*)d_in[10];
    const float* fcW = (const float*)d_in[11];
    const float* fcb = (const float*)d_in[12];
    float* out = (float*)d_out;

    float* ws = (float*)d_ws;
    int* flag = (int*)d_ws;                       // [1] (+pad to 256)
    __half* h16  = (__half*)(ws + 256);           // [N,256] fp16 [n][dim][head]
    float* as_   = (float*)(h16 + (size_t)NN * 256);  // [N,4]
    float* ad_   = as_ + NN * 4;                  // [N,4]
    float* xacc  = ad_ + NN * 4;                  // [N,64]
    int* src32   = (int*)(xacc + (size_t)NN * 64);// [E]
    int* dst32   = src32 + ETOT;                  // [E]
    int* deg     = dst32 + ETOT;                  // [N]
    int* rowptr  = deg + NN;                      // [N+1]
    int* cursor  = rowptr + NN + 1;               // [N]
    int* csr_src = cursor + NN;                   // [E]
    int* bsum    = csr_src + ETOT;                // [NBLK]
    int* boff    = bsum + NBLK;                   // [NBLK]

    const int eb = (ETOT + 255) / 256;    // 3321
    const int wb = (NN * 64 + 255) / 256; // 12500 (wave-per-node blocks)

    // ---- one-time per call: indices + dst-CSR ----
    k_detect<<<1, 64, 0, stream>>>(ei, flag);
    hipMemsetAsync(deg, 0, NN * sizeof(int), stream);
    k_prep<<<eb, 256, 0, stream>>>(ei, flag, src32, dst32, deg);
    k_blocksum<<<NBLK, 256, 0, stream>>>(deg, bsum);
    k_scan_bsum<<<1, 256, 0, stream>>>(bsum, boff);
    k_scan_final<<<NBLK, 256, 0, stream>>>(deg, boff, rowptr, cursor);
    k_scatter<<<eb, 256, 0, stream>>>(src32, dst32, cursor, csr_src);

    const int gg = (NN + 31) / 32;  // 1563 blocks, all 4 heads per block
    // ---- layer 1 ----
    k_gemm<128><<<gg, 256, 0, stream>>>(x, W1, a1s, a1d, h16, as_, ad_, NN);
    k_aggr<<<wb, 256, 0, stream>>>(rowptr, csr_src, as_, ad_, h16, b1, xacc);
    // ---- layer 2 ----
    k_gemm<64><<<gg, 256, 0, stream>>>(xacc, W2, a2s, a2d, h16, as_, ad_, NN);
    k_aggr<<<wb, 256, 0, stream>>>(rowptr, csr_src, as_, ad_, h16, b2, xacc);
    // ---- pool + fc ----
    k_pool_fc<<<NG, 256, 0, stream>>>(xacc, bat, flag, fcW, fcb, out);
}

// Round 10
// 435.274 us; speedup vs baseline: 1.5931x; 1.0520x over previous
//
#include <hip/hip_runtime.h>
#include <hip/hip_bf16.h>
#include <hip/hip_fp16.h>

#define NN 50000
#define EE 800000
#define ETOT 850000
#define NG 500
#define NBLK ((NN + 255) / 256)  // 196 scan blocks

// int64 vs int32 index detect: node ids < 50000, so int64 => odd words all 0.
__global__ void k_detect(const int* __restrict__ ei, int* __restrict__ flag) {
    unsigned long long b = __ballot(ei[2 * threadIdx.x + 1] != 0);
    if (threadIdx.x == 0) *flag = b ? 1 : 2;
}

// edge list -> int32 src/dst with self-loops appended; fused degree histogram.
__global__ __launch_bounds__(256) void k_prep(const int* __restrict__ ei,
                                              const int* __restrict__ flag,
                                              int* __restrict__ src32,
                                              int* __restrict__ dst32,
                                              int* __restrict__ deg) {
    int e = blockIdx.x * 256 + threadIdx.x;
    if (e >= ETOT) return;
    int st = *flag;
    int s, d;
    if (e < EE) {
        s = ei[(size_t)st * e];
        d = ei[(size_t)st * (EE + e)];
    } else {
        s = d = e - EE;  // self-loop
    }
    src32[e] = s;
    dst32[e] = d;
    atomicAdd(&deg[d], 1);
}

// ---- 3-phase multi-block exclusive scan of deg[NN] ----
__global__ __launch_bounds__(256) void k_blocksum(const int* __restrict__ deg,
                                                  int* __restrict__ bsum) {
    __shared__ int l[256];
    int gid = blockIdx.x * 256 + threadIdx.x;
    int tid = threadIdx.x;
    l[tid] = (gid < NN) ? deg[gid] : 0;
    __syncthreads();
    for (int o = 128; o > 0; o >>= 1) {
        if (tid < o) l[tid] += l[tid + o];
        __syncthreads();
    }
    if (tid == 0) bsum[blockIdx.x] = l[0];
}

__global__ __launch_bounds__(256) void k_scan_bsum(const int* __restrict__ bsum,
                                                   int* __restrict__ boff) {
    __shared__ int l[256];
    int tid = threadIdx.x;
    int v = (tid < NBLK) ? bsum[tid] : 0;
    l[tid] = v;
    __syncthreads();
    for (int d = 1; d < 256; d <<= 1) {
        int t = (tid >= d) ? l[tid - d] : 0;
        __syncthreads();
        l[tid] += t;
        __syncthreads();
    }
    if (tid < NBLK) boff[tid] = l[tid] - v;  // exclusive
}

__global__ __launch_bounds__(256) void k_scan_final(const int* __restrict__ deg,
                                                    const int* __restrict__ boff,
                                                    int* __restrict__ rowptr,
                                                    int* __restrict__ cursor) {
    __shared__ int l[256];
    int gid = blockIdx.x * 256 + threadIdx.x;
    int tid = threadIdx.x;
    int v = (gid < NN) ? deg[gid] : 0;
    l[tid] = v;
    __syncthreads();
    for (int d = 1; d < 256; d <<= 1) {
        int t = (tid >= d) ? l[tid - d] : 0;
        __syncthreads();
        l[tid] += t;
        __syncthreads();
    }
    int ex = l[tid] - v + boff[blockIdx.x];
    if (gid < NN) { rowptr[gid] = ex; cursor[gid] = ex; }
    if (gid == 0) rowptr[NN] = ETOT;  // total incl. self-loops is a constant
}

__global__ __launch_bounds__(256) void k_scatter(const int* __restrict__ src32,
                                                 const int* __restrict__ dst32,
                                                 int* __restrict__ cursor,
                                                 int* __restrict__ csr_src) {
    int e = blockIdx.x * 256 + threadIdx.x;
    if (e >= ETOT) return;
    int pos = atomicAdd(&cursor[dst32[e]], 1);
    csr_src[pos] = src32[e];
}

// C[M,256] = A[M,K] @ B[K,256]. BM=32, BN=256 (all 4 heads), BK=16, 256 thr;
// thread tile 2 rows x 16 cols. Interleaved fp16 epilogue (16 contiguous
// halves/row/thread -> zero write amplification) + fused alpha epilogue.
template <int K>
__global__ __launch_bounds__(256) void k_gemm(const float* __restrict__ A,
                                              const float* __restrict__ B,
                                              const float* __restrict__ asrc,
                                              const float* __restrict__ adst,
                                              __half* __restrict__ C16,
                                              float* __restrict__ os,
                                              float* __restrict__ od, int M) {
    __shared__ float As[16][34];   // [k][m]
    __shared__ float Bs[16][260];  // [k][n]
    const int m0 = blockIdx.x * 32;
    const int tid = threadIdx.x;
    const int tx = tid & 15, ty = tid >> 4;  // tx: dim-group, ty: 2-row group
    float acc[2][16] = {};  // acc[i][h*4+jd]: row ty*2+i, col h*64+tx*4+jd
    for (int k0 = 0; k0 < K; k0 += 16) {
        {   // A tile: 32 rows x 16 k; thread loads float2 along k
            int r = tid >> 3, c = (tid & 7) * 2;
            int gm = m0 + r;
            float2 av = (gm < M) ? *(const float2*)(A + gm * K + k0 + c)
                                 : make_float2(0.f, 0.f);
            As[c][r] = av.x;
            As[c + 1][r] = av.y;
        }
        {   // B tile: 16 k x 256 n; float4 loads (4 passes)
            int col = (tid & 63) * 4, rb = tid >> 6;
#pragma unroll
            for (int p = 0; p < 4; ++p) {
                int row = p * 4 + rb;
                *(float4*)&Bs[row][col] = *(const float4*)(B + (k0 + row) * 256 + col);
            }
        }
        __syncthreads();
#pragma unroll
        for (int k = 0; k < 16; ++k) {
            float a0 = As[k][ty * 2], a1 = As[k][ty * 2 + 1];
            float b[16];
#pragma unroll
            for (int h = 0; h < 4; ++h)
                *(float4*)&b[h * 4] = *(const float4*)&Bs[k][h * 64 + tx * 4];
#pragma unroll
            for (int j = 0; j < 16; ++j) {
                acc[0][j] += a0 * b[j];
                acc[1][j] += a1 * b[j];
            }
        }
        __syncthreads();
    }
    // interleaved fp16 store: memory index (tx*4+jd)*4+h = tx*16 + jd*4 + h
#pragma unroll
    for (int i = 0; i < 2; ++i) {
        int gm = m0 + ty * 2 + i;
        if (gm < M) {
            __half hbuf[16];
#pragma unroll
            for (int jd = 0; jd < 4; ++jd) {
                __half2 p0 = __floats2half2_rn(acc[i][0 * 4 + jd], acc[i][1 * 4 + jd]);
                __half2 p1 = __floats2half2_rn(acc[i][2 * 4 + jd], acc[i][3 * 4 + jd]);
                *(__half2*)&hbuf[jd * 4]     = p0;
                *(__half2*)&hbuf[jd * 4 + 2] = p1;
            }
            *(uint4*)(C16 + gm * 256 + tx * 16)     = *(uint4*)&hbuf[0];
            *(uint4*)(C16 + gm * 256 + tx * 16 + 8) = *(uint4*)&hbuf[8];
        }
    }
    // fused alpha_s / alpha_d (fp32), all 4 heads in-thread
    float ps[2][4], pd[2][4];  // [row][head]
#pragma unroll
    for (int h = 0; h < 4; ++h) {
        float4 av = *(const float4*)&asrc[h * 64 + tx * 4];
        float4 dv = *(const float4*)&adst[h * 64 + tx * 4];
#pragma unroll
        for (int i = 0; i < 2; ++i) {
            ps[i][h] = acc[i][h * 4 + 0] * av.x + acc[i][h * 4 + 1] * av.y +
                       acc[i][h * 4 + 2] * av.z + acc[i][h * 4 + 3] * av.w;
            pd[i][h] = acc[i][h * 4 + 0] * dv.x + acc[i][h * 4 + 1] * dv.y +
                       acc[i][h * 4 + 2] * dv.z + acc[i][h * 4 + 3] * dv.w;
        }
    }
#pragma unroll
    for (int off = 1; off < 16; off <<= 1) {
#pragma unroll
        for (int i = 0; i < 2; ++i)
#pragma unroll
            for (int h = 0; h < 4; ++h) {
                ps[i][h] += __shfl_xor(ps[i][h], off);
                pd[i][h] += __shfl_xor(pd[i][h], off);
            }
    }
    if (tx == 0) {
#pragma unroll
        for (int i = 0; i < 2; ++i) {
            int gm = m0 + ty * 2 + i;
            if (gm < M) {
                *(float4*)(os + gm * 4) = make_float4(ps[i][0], ps[i][1], ps[i][2], ps[i][3]);
                *(float4*)(od + gm * 4) = make_float4(pd[i][0], pd[i][1], pd[i][2], pd[i][3]);
            }
        }
    }
}

__device__ __forceinline__ float lrelu_exp(float x) {
    x = x > 0.f ? x : 0.2f * x;
    return __expf(x);
}

// Wave per dst node. h16 [n][dim][head]: lane=dim -> ONE 8B gather per edge.
// Chunk 0 (deg<=64, ~all nodes) runs a 4-deep explicit register pipeline:
// next quad of gathers issued BEFORE consuming current quad -> 4-8 loads in
// flight per wave (r9 measured ~1 in flight -> 2.75 TB/s latency-bound).
// Free invariant: lanes >= cnt hold s0=0 (safe address) and al=0 (zero
// contribution), so the loop runs guard-free on cnt rounded up to 4.
__global__ __launch_bounds__(256) void k_aggr(const int* __restrict__ rowptr,
                                              const int* __restrict__ csr_src,
                                              const float* __restrict__ as_,
                                              const float* __restrict__ ad_,
                                              const __half* __restrict__ h16,
                                              const float* __restrict__ bias,
                                              float* __restrict__ out) {
    int d = (blockIdx.x * 256 + threadIdx.x) >> 6;
    int lane = threadIdx.x & 63;
    if (d >= NN) return;
    int beg = rowptr[d], end = rowptr[d + 1];
    float4 adv = *(const float4*)(ad_ + d * 4);

    // pass 1: denominator + chunk-0 register cache
    int s0 = 0;
    float4 u0 = make_float4(0.f, 0.f, 0.f, 0.f);
    float4 den = make_float4(0.f, 0.f, 0.f, 0.f);
    int i0 = beg + lane;
    if (i0 < end) {
        s0 = csr_src[i0];
        float4 sv = *(const float4*)(as_ + s0 * 4);
        u0.x = lrelu_exp(sv.x + adv.x);
        u0.y = lrelu_exp(sv.y + adv.y);
        u0.z = lrelu_exp(sv.z + adv.z);
        u0.w = lrelu_exp(sv.w + adv.w);
        den = u0;
    }
    for (int i = i0 + 64; i < end; i += 64) {
        int s = csr_src[i];
        float4 sv = *(const float4*)(as_ + s * 4);
        den.x += lrelu_exp(sv.x + adv.x);
        den.y += lrelu_exp(sv.y + adv.y);
        den.z += lrelu_exp(sv.z + adv.z);
        den.w += lrelu_exp(sv.w + adv.w);
    }
#pragma unroll
    for (int off = 32; off > 0; off >>= 1) {
        den.x += __shfl_xor(den.x, off);
        den.y += __shfl_xor(den.y, off);
        den.z += __shfl_xor(den.z, off);
        den.w += __shfl_xor(den.w, off);
    }
    float4 dinv = make_float4(0.25f / den.x, 0.25f / den.y,
                              0.25f / den.z, 0.25f / den.w);

    // pass 2, chunk 0: pipelined. al=0 on lanes >= cnt, s0=0 there (safe).
    float4 al0 = make_float4(u0.x * dinv.x, u0.y * dinv.y,
                             u0.z * dinv.z, u0.w * dinv.w);
    int cnt = end - beg;
    if (cnt > 64) cnt = 64;
    int cnt4 = (cnt + 3) & ~3;
    float acc = 0.f;
    uint2 r0, r1, r2, r3;
    {
        int sa = __shfl(s0, 0), sb = __shfl(s0, 1);
        int sc = __shfl(s0, 2), sd = __shfl(s0, 3);
        r0 = *(const uint2*)(h16 + (size_t)sa * 256 + lane * 4);
        r1 = *(const uint2*)(h16 + (size_t)sb * 256 + lane * 4);
        r2 = *(const uint2*)(h16 + (size_t)sc * 256 + lane * 4);
        r3 = *(const uint2*)(h16 + (size_t)sd * 256 + lane * 4);
    }
    for (int j = 0; j < cnt4; j += 4) {
        // issue next quad first (wrap keeps shfl index valid; loads redundant
        // but safe on the final iteration)
        int sa = __shfl(s0, (j + 4) & 63), sb = __shfl(s0, (j + 5) & 63);
        int sc = __shfl(s0, (j + 6) & 63), sd = __shfl(s0, (j + 7) & 63);
        uint2 n0 = *(const uint2*)(h16 + (size_t)sa * 256 + lane * 4);
        uint2 n1 = *(const uint2*)(h16 + (size_t)sb * 256 + lane * 4);
        uint2 n2 = *(const uint2*)(h16 + (size_t)sc * 256 + lane * 4);
        uint2 n3 = *(const uint2*)(h16 + (size_t)sd * 256 + lane * 4);
        // consume current quad
        float a00 = __shfl(al0.x, j),     a01 = __shfl(al0.y, j),     a02 = __shfl(al0.z, j),     a03 = __shfl(al0.w, j);
        float a10 = __shfl(al0.x, j + 1), a11 = __shfl(al0.y, j + 1), a12 = __shfl(al0.z, j + 1), a13 = __shfl(al0.w, j + 1);
        float a20 = __shfl(al0.x, j + 2), a21 = __shfl(al0.y, j + 2), a22 = __shfl(al0.z, j + 2), a23 = __shfl(al0.w, j + 2);
        float a30 = __shfl(al0.x, j + 3), a31 = __shfl(al0.y, j + 3), a32 = __shfl(al0.z, j + 3), a33 = __shfl(al0.w, j + 3);
        float2 fa, fb;
        fa = __half22float2(*(const __half2*)&r0.x);
        fb = __half22float2(*(const __half2*)&r0.y);
        acc += a00 * fa.x + a01 * fa.y + a02 * fb.x + a03 * fb.y;
        fa = __half22float2(*(const __half2*)&r1.x);
        fb = __half22float2(*(const __half2*)&r1.y);
        acc += a10 * fa.x + a11 * fa.y + a12 * fb.x + a13 * fb.y;
        fa = __half22float2(*(const __half2*)&r2.x);
        fb = __half22float2(*(const __half2*)&r2.y);
        acc += a20 * fa.x + a21 * fa.y + a22 * fb.x + a23 * fb.y;
        fa = __half22float2(*(const __half2*)&r3.x);
        fb = __half22float2(*(const __half2*)&r3.y);
        acc += a30 * fa.x + a31 * fa.y + a32 * fb.x + a33 * fb.y;
        r0 = n0; r1 = n1; r2 = n2; r3 = n3;
    }
    // rare chunks >= 1 (deg > 64): simple path
    for (int chunk = beg + 64; chunk < end; chunk += 64) {
        int i = chunk + lane;
        int s = 0;
        float4 al = make_float4(0.f, 0.f, 0.f, 0.f);
        if (i < end) {
            s = csr_src[i];
            float4 sv = *(const float4*)(as_ + s * 4);
            al.x = lrelu_exp(sv.x + adv.x) * dinv.x;
            al.y = lrelu_exp(sv.y + adv.y) * dinv.y;
            al.z = lrelu_exp(sv.z + adv.z) * dinv.z;
            al.w = lrelu_exp(sv.w + adv.w) * dinv.w;
        }
        int cc = end - chunk;
        if (cc > 64) cc = 64;
        for (int j = 0; j < cc; ++j) {
            int sj = __shfl(s, j);
            float a0 = __shfl(al.x, j), a1 = __shfl(al.y, j);
            float a2 = __shfl(al.z, j), a3 = __shfl(al.w, j);
            uint2 raw = *(const uint2*)(h16 + (size_t)sj * 256 + lane * 4);
            float2 fa = __half22float2(*(const __half2*)&raw.x);
            float2 fb = __half22float2(*(const __half2*)&raw.y);
            acc += a0 * fa.x + a1 * fa.y + a2 * fb.x + a3 * fb.y;
        }
    }
    float v = acc + bias[lane];
    out[d * 64 + lane] = v > 0.f ? v : 0.f;
}

// batch is SORTED: binary-search the node range per graph. 4 waves split the
// node loop.
__global__ __launch_bounds__(256) void k_pool_fc(const float* __restrict__ x3,
                                                 const int* __restrict__ batch,
                                                 const int* __restrict__ flag,
                                                 const float* __restrict__ fcW,
                                                 const float* __restrict__ fcb,
                                                 float* __restrict__ out) {
    int g = blockIdx.x;
    int tid = threadIdx.x, lane = tid & 63, w = tid >> 6;
    int st = *flag;
    int lo = 0, hi = NN;
    while (lo < hi) { int mid = (lo + hi) >> 1; if (batch[(size_t)st * mid] < g) lo = mid + 1; else hi = mid; }
    int start = lo;
    hi = NN;
    while (lo < hi) { int mid = (lo + hi) >> 1; if (batch[(size_t)st * mid] < g + 1) lo = mid + 1; else hi = mid; }
    int end = lo;
    float sum = 0.f;
    for (int n = start + w; n < end; n += 4) sum += x3[n * 64 + lane];
    __shared__ float ls[4][64];
    ls[w][lane] = sum;
    __syncthreads();
    if (w == 0) {
        float c = (float)(end - start);
        if (c < 1.f) c = 1.f;
        float p = (ls[0][lane] + ls[1][lane] + ls[2][lane] + ls[3][lane]) / c;
#pragma unroll
        for (int o = 0; o < 16; ++o) {
            float v = p * fcW[lane * 16 + o];
#pragma unroll
            for (int off = 32; off > 0; off >>= 1) v += __shfl_down(v, off);
            if (lane == 0) out[g * 16 + o] = v + fcb[o];
        }
    }
}

extern "C" void kernel_launch(void* const* d_in, const int* in_sizes, int n_in,
                              void* d_out, int out_size, void* d_ws, size_t ws_size,
                              hipStream_t stream) {
    const float* x   = (const float*)d_in[0];
    const int*   ei  = (const int*)d_in[1];
    const int*   bat = (const int*)d_in[2];
    const float* W1  = (const float*)d_in[3];
    const float* a1s = (const float*)d_in[4];
    const float* a1d = (const float*)d_in[5];
    const float* b1  = (const float*)d_in[6];
    const float* W2  = (const float*)d_in[7];
    const float* a2s = (const float*)d_in[8];
    const float* a2d = (const float*)d_in[9];
    const float* b2  = (const float*)d_in[10];
    const float* fcW = (const float*)d_in[11];
    const float* fcb = (const float*)d_in[12];
    float* out = (float*)d_out;

    float* ws = (float*)d_ws;
    int* flag = (int*)d_ws;                       // [1] (+pad to 256)
    __half* h16  = (__half*)(ws + 256);           // [N,256] fp16 [n][dim][head]
    float* as_   = (float*)(h16 + (size_t)NN * 256);  // [N,4]
    float* ad_   = as_ + NN * 4;                  // [N,4]
    float* xacc  = ad_ + NN * 4;                  // [N,64]
    int* src32   = (int*)(xacc + (size_t)NN * 64);// [E]
    int* dst32   = src32 + ETOT;                  // [E]
    int* deg     = dst32 + ETOT;                  // [N]
    int* rowptr  = deg + NN;                      // [N+1]
    int* cursor  = rowptr + NN + 1;               // [N]
    int* csr_src = cursor + NN;                   // [E]
    int* bsum    = csr_src + ETOT;                // [NBLK]
    int* boff    = bsum + NBLK;                   // [NBLK]

    const int eb = (ETOT + 255) / 256;    // 3321
    const int wb = (NN * 64 + 255) / 256; // 12500 (wave-per-node blocks)

    // ---- one-time per call: indices + dst-CSR ----
    k_detect<<<1, 64, 0, stream>>>(ei, flag);
    hipMemsetAsync(deg, 0, NN * sizeof(int), stream);
    k_prep<<<eb, 256, 0, stream>>>(ei, flag, src32, dst32, deg);
    k_blocksum<<<NBLK, 256, 0, stream>>>(deg, bsum);
    k_scan_bsum<<<1, 256, 0, stream>>>(bsum, boff);
    k_scan_final<<<NBLK, 256, 0, stream>>>(deg, boff, rowptr, cursor);
    k_scatter<<<eb, 256, 0, stream>>>(src32, dst32, cursor, csr_src);

    const int gg = (NN + 31) / 32;  // 1563 blocks, all 4 heads per block
    // ---- layer 1 ----
    k_gemm<128><<<gg, 256, 0, stream>>>(x, W1, a1s, a1d, h16, as_, ad_, NN);
    k_aggr<<<wb, 256, 0, stream>>>(rowptr, csr_src, as_, ad_, h16, b1, xacc);
    // ---- layer 2 ----
    k_gemm<64><<<gg, 256, 0, stream>>>(xacc, W2, a2s, a2d, h16, as_, ad_, NN);
    k_aggr<<<wb, 256, 0, stream>>>(rowptr, csr_src, as_, ad_, h16, b2, xacc);
    // ---- pool + fc ----
    k_pool_fc<<<NG, 256, 0, stream>>>(xacc, bat, flag, fcW, fcb, out);
}